// Round 2
// baseline (1340.201 us; speedup 1.0000x reference)
//
#include <hip/hip_runtime.h>
#include <math.h>

// ---------------------------------------------------------------------------
// MultiModalFusionGAT
//   4 node types (user/item/taste/image), HID=128, H=8, DH=16.
//   Per-type fused projection: kr = x @ (Wk*blockdiag(a_rel[et])) + b',
//                              vr = x @ (Wv*blockdiag(m_rel[et])) + b',
//                              q  = x @ Wq + bq   (item/user only)
//   Edge softmax-attention aggregation via 3 atomic passes, then
//   GELU -> GEMM -> skip-gate epilogue.
//
// Workspace budget (fp32, reuse-aware): 53,732,096 floats = 214.9 MB
//   - exp-buffer lives in d_out (dead until epilogue, fully rewritten)
//   - agg accumulators reuse the kr region (dead after pass A)
// ---------------------------------------------------------------------------

namespace {
constexpr int HIDN  = 128;
constexpr int NHEAD = 8;
constexpr int DHEAD = 16;

constexpr int NU = 20000, NI = 50000, NT = 50000, NG = 50000;
constexpr int E_TI = 50000, E_IM = 50000, E_UB = 500000, E_BU = 500000;
}

// cw layout: [which(2)][type(4)][row(129)][col(128)]; row 128 = transformed bias
__global__ void build_cw_kernel(const float* __restrict__ Wk, const float* __restrict__ bk,
                                const float* __restrict__ Wv, const float* __restrict__ bv,
                                const float* __restrict__ a_rel, const float* __restrict__ m_rel,
                                float* __restrict__ cw)
{
    const int total = 2 * 4 * 129 * 128;
    int idx = blockIdx.x * blockDim.x + threadIdx.x;
    if (idx >= total) return;
    int c     = idx & 127;
    int r     = (idx >> 7) % 129;
    int t     = ((idx >> 7) / 129) & 3;
    int which = idx / (4 * 129 * 128);
    const int et_map[4] = {2, 3, 0, 1};   // node type -> edge type whose rel-mat applies
    int et = et_map[t];
    const float* W = (which == 0 ? Wk : Wv) + (size_t)t * HIDN * HIDN;
    const float* b = (which == 0 ? bk : bv) + (size_t)t * HIDN;
    const float* A = (which == 0 ? a_rel : m_rel) + (size_t)et * NHEAD * DHEAD * DHEAD;
    int h = c >> 4, e2 = c & 15;
    float s = 0.f;
#pragma unroll
    for (int d = 0; d < DHEAD; ++d) {
        float w = (r == 128) ? b[h * DHEAD + d] : W[(size_t)r * HIDN + h * DHEAD + d];
        s = fmaf(w, A[h * DHEAD * DHEAD + d * DHEAD + e2], s);
    }
    cw[idx] = s;
}

// One block = 16 rows of x; 128 threads, thread j owns output column j.
__global__ __launch_bounds__(128) void proj_kernel(
    const float* __restrict__ x, int N,
    const float* __restrict__ cwk,   // [129][128] (row 128 = bias)
    const float* __restrict__ cwv,   // [129][128]
    const float* __restrict__ Wq,    // [128][128] or nullptr
    const float* __restrict__ bq,    // [128] or nullptr
    float* __restrict__ kr, float* __restrict__ vr, float* __restrict__ q)
{
    __shared__ float xs[16][HIDN];
    const int j  = threadIdx.x;
    const int r0 = blockIdx.x * 16;
    int rows = N - r0; if (rows > 16) rows = 16;

    for (int r = 0; r < rows; ++r)
        xs[r][j] = x[(size_t)(r0 + r) * HIDN + j];
    __syncthreads();

    float ak[16], av[16], aq[16];
    const float bkv = cwk[128 * HIDN + j];
    const float bvv = cwv[128 * HIDN + j];
    const float bqv = (q != nullptr) ? bq[j] : 0.f;
#pragma unroll
    for (int r = 0; r < 16; ++r) { ak[r] = bkv; av[r] = bvv; aq[r] = bqv; }

    if (q != nullptr) {
        for (int kk = 0; kk < HIDN; ++kk) {
            float wk = cwk[kk * HIDN + j];
            float wv = cwv[kk * HIDN + j];
            float wq = Wq[kk * HIDN + j];
#pragma unroll
            for (int r = 0; r < 16; ++r) {
                float xv = xs[r][kk];
                ak[r] = fmaf(xv, wk, ak[r]);
                av[r] = fmaf(xv, wv, av[r]);
                aq[r] = fmaf(xv, wq, aq[r]);
            }
        }
    } else {
        for (int kk = 0; kk < HIDN; ++kk) {
            float wk = cwk[kk * HIDN + j];
            float wv = cwv[kk * HIDN + j];
#pragma unroll
            for (int r = 0; r < 16; ++r) {
                float xv = xs[r][kk];
                ak[r] = fmaf(xv, wk, ak[r]);
                av[r] = fmaf(xv, wv, av[r]);
            }
        }
    }

    for (int r = 0; r < rows; ++r) {
        kr[(size_t)(r0 + r) * HIDN + j] = ak[r];
        vr[(size_t)(r0 + r) * HIDN + j] = av[r];
        if (q != nullptr) q[(size_t)(r0 + r) * HIDN + j] = aq[r];
    }
}

__device__ __forceinline__ unsigned float_order_key(float f) {
    unsigned u = __float_as_uint(f);
    return (u & 0x80000000u) ? ~u : (u | 0x80000000u);
}
__device__ __forceinline__ float float_order_unkey(unsigned u) {
    return (u & 0x80000000u) ? __uint_as_float(u ^ 0x80000000u) : __uint_as_float(~u);
}

// Pass A: alpha per (edge, head); store alpha; atomicMax per (dst, head).
__global__ void edge_alpha_kernel(const int* __restrict__ src, const int* __restrict__ dst, int E,
                                  const float* __restrict__ kr, const float* __restrict__ q,
                                  const float* __restrict__ prow,
                                  float* __restrict__ exbuf, unsigned* __restrict__ amax)
{
    int idx = blockIdx.x * blockDim.x + threadIdx.x;
    if (idx >= E * NHEAD) return;
    int e = idx >> 3, h = idx & 7;
    int s = src[e], d = dst[e];
    const float4* qp = (const float4*)(q  + (size_t)d * HIDN + h * DHEAD);
    const float4* kp = (const float4*)(kr + (size_t)s * HIDN + h * DHEAD);
    float acc = 0.f;
#pragma unroll
    for (int i = 0; i < 4; ++i) {
        float4 a4 = qp[i], b4 = kp[i];
        acc += a4.x * b4.x + a4.y * b4.y + a4.z * b4.z + a4.w * b4.w;
    }
    float alpha = acc * prow[h] * 0.25f;   // 1/sqrt(16)
    exbuf[idx] = alpha;
    atomicMax(amax + (size_t)d * NHEAD + h, float_order_key(alpha));
}

// Pass B: ex = exp(alpha - max); overwrite exbuf; atomicAdd denom.
__global__ void edge_expden_kernel(const int* __restrict__ dst, int E,
                                   const unsigned* __restrict__ amax,
                                   float* __restrict__ exbuf, float* __restrict__ den)
{
    int idx = blockIdx.x * blockDim.x + threadIdx.x;
    if (idx >= E * NHEAD) return;
    int e = idx >> 3, h = idx & 7;
    int d = dst[e];
    float m  = float_order_unkey(amax[(size_t)d * NHEAD + h]);
    float ex = expf(exbuf[idx] - m);
    exbuf[idx] = ex;
    atomicAdd(den + (size_t)d * NHEAD + h, ex);
}

// Pass C: agg[dst] += (ex/den) * vr[src]; 128 consecutive threads per edge.
__global__ void edge_agg_kernel(const int* __restrict__ src, const int* __restrict__ dst, int E,
                                const float* __restrict__ vr, const float* __restrict__ exbuf,
                                const float* __restrict__ den, float* __restrict__ agg)
{
    long long idx = (long long)blockIdx.x * blockDim.x + threadIdx.x;
    if (idx >= (long long)E * HIDN) return;
    int e = (int)(idx >> 7);
    int j = (int)(idx & 127);
    int h = j >> 4;
    int s = src[e], d = dst[e];
    float w = exbuf[(size_t)e * NHEAD + h] / (den[(size_t)d * NHEAD + h] + 1e-16f);
    atomicAdd(agg + (size_t)d * HIDN + j, w * vr[(size_t)s * HIDN + j]);
}

// Epilogue: out = gate * (gelu(agg) @ Wo + bo) + (1-gate) * x_in
__global__ __launch_bounds__(128) void out_gemm_kernel(
    const float* __restrict__ agg, const float* __restrict__ xin,
    const float* __restrict__ Wo, const float* __restrict__ bo,
    const float* __restrict__ skip_ptr,
    float* __restrict__ out, int N)
{
    __shared__ float gs[16][HIDN];
    const int j  = threadIdx.x;
    const int r0 = blockIdx.x * 16;
    int rows = N - r0; if (rows > 16) rows = 16;

    for (int r = 0; r < rows; ++r) {
        float v = agg[(size_t)(r0 + r) * HIDN + j];
        gs[r][j] = 0.5f * v * (1.0f + erff(v * 0.70710678118654752440f));
    }
    __syncthreads();

    float acc[16];
    const float b = bo[j];
#pragma unroll
    for (int r = 0; r < 16; ++r) acc[r] = b;

    for (int kk = 0; kk < HIDN; ++kk) {
        float w = Wo[kk * HIDN + j];
#pragma unroll
        for (int r = 0; r < 16; ++r)
            acc[r] = fmaf(gs[r][kk], w, acc[r]);
    }

    float gate = 1.f / (1.f + expf(-skip_ptr[0]));
    for (int r = 0; r < rows; ++r)
        out[(size_t)(r0 + r) * HIDN + j] =
            gate * acc[r] + (1.f - gate) * xin[(size_t)(r0 + r) * HIDN + j];
}

extern "C" void kernel_launch(void* const* d_in, const int* in_sizes, int n_in,
                              void* d_out, int out_size, void* d_ws, size_t ws_size,
                              hipStream_t stream)
{
    const float* x_user = (const float*)d_in[0];
    const float* x_item = (const float*)d_in[1];
    const float* x_taste= (const float*)d_in[2];
    const float* x_image= (const float*)d_in[3];
    const float* Wk     = (const float*)d_in[4];
    const float* bk     = (const float*)d_in[5];
    const float* Wq     = (const float*)d_in[6];
    const float* bq     = (const float*)d_in[7];
    const float* Wv     = (const float*)d_in[8];
    const float* bv     = (const float*)d_in[9];
    const float* a_rel  = (const float*)d_in[10];
    const float* m_rel  = (const float*)d_in[11];
    const float* p_rel  = (const float*)d_in[12];
    const float* Wo     = (const float*)d_in[13];
    const float* bo     = (const float*)d_in[14];
    const float* skip   = (const float*)d_in[15];
    const int* ti_src = (const int*)d_in[16];
    const int* ti_dst = (const int*)d_in[17];
    const int* im_src = (const int*)d_in[18];
    const int* im_dst = (const int*)d_in[19];
    const int* ub_src = (const int*)d_in[20];
    const int* ub_dst = (const int*)d_in[21];
    const int* bu_src = (const int*)d_in[22];
    const int* bu_dst = (const int*)d_in[23];

    float* ws = (float*)d_ws;
    float* outp = (float*)d_out;
    (void)in_sizes; (void)n_in; (void)out_size;

    // ---- workspace layout (floats) — total 53,732,096 fl = 214.9 MB ----
    size_t off = 0;
    auto alloc = [&](size_t n) { size_t o = off; off += n; return o; };
    const size_t o_cwk  = alloc((size_t)4 * 129 * 128);
    const size_t o_cwv  = alloc((size_t)4 * 129 * 128);
    // kr region: [kr_u | kr_i | kr_t | kr_g]; REUSED as [agg_i | agg_u] after pass A
    const size_t o_kr   = alloc((size_t)(NU + NI + NT + NG) * HIDN);
    const size_t o_kr_u = o_kr;
    const size_t o_kr_i = o_kr_u + (size_t)NU * HIDN;
    const size_t o_kr_t = o_kr_i + (size_t)NI * HIDN;
    const size_t o_kr_g = o_kr_t + (size_t)NT * HIDN;
    const size_t o_vr   = alloc((size_t)(NU + NI + NT + NG) * HIDN);
    const size_t o_vr_u = o_vr;
    const size_t o_vr_i = o_vr_u + (size_t)NU * HIDN;
    const size_t o_vr_t = o_vr_i + (size_t)NI * HIDN;
    const size_t o_vr_g = o_vr_t + (size_t)NT * HIDN;
    const size_t o_q_i  = alloc((size_t)NI * HIDN);
    const size_t o_q_u  = alloc((size_t)NU * HIDN);
    // zero region 1: amax + den
    const size_t o_zero1  = off;
    const size_t o_amax_i = alloc((size_t)NI * NHEAD);
    const size_t o_amax_u = alloc((size_t)NU * NHEAD);
    const size_t o_den_i  = alloc((size_t)NI * NHEAD);
    const size_t o_den_u  = alloc((size_t)NU * NHEAD);
    const size_t zero1_bytes = (off - o_zero1) * sizeof(float);

    if (ws_size < off * sizeof(float)) return;  // clean failure instead of OOB fault

    // exp-buffer lives in d_out (8.8M <= 8.96M); agg reuses kr region
    const size_t o_agg_i = o_kr;                          // 6.4M fl
    const size_t o_agg_u = o_kr + (size_t)NI * HIDN;      // 2.56M fl
    float* ex_i = outp;                                   // 4.8M fl
    float* ex_u = outp + (size_t)(E_TI + E_IM + E_UB) * NHEAD;  // 4.0M fl
    const size_t agg_bytes = (size_t)(NI + NU) * HIDN * sizeof(float);

    // ---- 1. combined relation-fused weights ----
    {
        int total = 2 * 4 * 129 * 128;
        build_cw_kernel<<<(total + 255) / 256, 256, 0, stream>>>(
            Wk, bk, Wv, bv, a_rel, m_rel, ws + o_cwk);
    }

    // zero amax/den (before pass A)
    hipMemsetAsync(ws + o_zero1, 0, zero1_bytes, stream);

    // ---- 2. fused projections per node type ----
    proj_kernel<<<(NU + 15) / 16, 128, 0, stream>>>(
        x_user, NU, ws + o_cwk + 0 * 129 * 128, ws + o_cwv + 0 * 129 * 128,
        Wq + 0 * HIDN * HIDN, bq + 0 * HIDN,
        ws + o_kr_u, ws + o_vr_u, ws + o_q_u);
    proj_kernel<<<(NI + 15) / 16, 128, 0, stream>>>(
        x_item, NI, ws + o_cwk + 1 * 129 * 128, ws + o_cwv + 1 * 129 * 128,
        Wq + 1 * HIDN * HIDN, bq + 1 * HIDN,
        ws + o_kr_i, ws + o_vr_i, ws + o_q_i);
    proj_kernel<<<(NT + 15) / 16, 128, 0, stream>>>(
        x_taste, NT, ws + o_cwk + 2 * 129 * 128, ws + o_cwv + 2 * 129 * 128,
        nullptr, nullptr,
        ws + o_kr_t, ws + o_vr_t, nullptr);
    proj_kernel<<<(NG + 15) / 16, 128, 0, stream>>>(
        x_image, NG, ws + o_cwk + 3 * 129 * 128, ws + o_cwv + 3 * 129 * 128,
        nullptr, nullptr,
        ws + o_kr_g, ws + o_vr_g, nullptr);

    // ---- 3. pass A: alpha + segment max (ex written into d_out) ----
    auto launchA = [&](const int* s, const int* d, int E, size_t o_kr_, size_t o_q_,
                       int et, float* ex, size_t o_amax) {
        int n = E * NHEAD;
        edge_alpha_kernel<<<(n + 255) / 256, 256, 0, stream>>>(
            s, d, E, ws + o_kr_, ws + o_q_, p_rel + et * NHEAD,
            ex, (unsigned*)(ws + o_amax));
    };
    launchA(ti_src, ti_dst, E_TI, o_kr_t, o_q_i, 0, ex_i,                              o_amax_i);
    launchA(im_src, im_dst, E_IM, o_kr_g, o_q_i, 1, ex_i + (size_t)E_TI * NHEAD,       o_amax_i);
    launchA(ub_src, ub_dst, E_UB, o_kr_u, o_q_i, 2, ex_i + (size_t)(E_TI + E_IM) * NHEAD, o_amax_i);
    launchA(bu_src, bu_dst, E_BU, o_kr_i, o_q_u, 3, ex_u,                              o_amax_u);

    // zero agg (kr region dead after pass A; stream order guarantees safety)
    hipMemsetAsync(ws + o_agg_i, 0, agg_bytes, stream);

    // ---- 4. pass B: exp + denom ----
    auto launchB = [&](const int* d, int E, float* ex, size_t o_amax, size_t o_den) {
        int n = E * NHEAD;
        edge_expden_kernel<<<(n + 255) / 256, 256, 0, stream>>>(
            d, E, (const unsigned*)(ws + o_amax), ex, ws + o_den);
    };
    launchB(ti_dst, E_TI, ex_i,                                 o_amax_i, o_den_i);
    launchB(im_dst, E_IM, ex_i + (size_t)E_TI * NHEAD,          o_amax_i, o_den_i);
    launchB(ub_dst, E_UB, ex_i + (size_t)(E_TI + E_IM) * NHEAD, o_amax_i, o_den_i);
    launchB(bu_dst, E_BU, ex_u,                                 o_amax_u, o_den_u);

    // ---- 5. pass C: weighted scatter-add of messages ----
    auto launchC = [&](const int* s, const int* d, int E, size_t o_vr_,
                       const float* ex, size_t o_den, size_t o_agg) {
        long long n = (long long)E * HIDN;
        edge_agg_kernel<<<(unsigned)((n + 255) / 256), 256, 0, stream>>>(
            s, d, E, ws + o_vr_, ex, ws + o_den, ws + o_agg);
    };
    launchC(ti_src, ti_dst, E_TI, o_vr_t, ex_i,                                 o_den_i, o_agg_i);
    launchC(im_src, im_dst, E_IM, o_vr_g, ex_i + (size_t)E_TI * NHEAD,          o_den_i, o_agg_i);
    launchC(ub_src, ub_dst, E_UB, o_vr_u, ex_i + (size_t)(E_TI + E_IM) * NHEAD, o_den_i, o_agg_i);
    launchC(bu_src, bu_dst, E_BU, o_vr_i, ex_u,                                 o_den_u, o_agg_u);

    // ---- 6. epilogue GEMMs (read agg from reused kr region, overwrite d_out) ----
    out_gemm_kernel<<<(NI + 15) / 16, 128, 0, stream>>>(
        ws + o_agg_i, x_item, Wo + 0 * HIDN * HIDN, bo + 0 * HIDN, skip + 0,
        outp, NI);
    out_gemm_kernel<<<(NU + 15) / 16, 128, 0, stream>>>(
        ws + o_agg_u, x_user, Wo + 1 * HIDN * HIDN, bo + 1 * HIDN, skip + 1,
        outp + (size_t)NI * HIDN, NU);
}

// Round 3
// 1060.519 us; speedup vs baseline: 1.2637x; 1.2637x over previous
//
#include <hip/hip_runtime.h>
#include <math.h>

// ---------------------------------------------------------------------------
// MultiModalFusionGAT — round 3
//   Node-level GEMMs (projections + epilogue) moved to split-bf16 MFMA
//   (hi/lo decomposition, 3 MFMA per product => ~fp32 accuracy at bf16 rate).
//   Edge softmax-attention aggregation unchanged (3 atomic passes).
// ---------------------------------------------------------------------------

namespace {
constexpr int HIDN  = 128;
constexpr int NHEAD = 8;
constexpr int DHEAD = 16;

constexpr int NU = 20000, NI = 50000, NT = 50000, NG = 50000;
constexpr int E_TI = 50000, E_IM = 50000, E_UB = 500000, E_BU = 500000;

constexpr int NMAT = 12;           // 0..3 k, 4..7 v, 8/9 q(user,item), 10/11 Wo(item,user)
constexpr int MATSZ = 128 * 128;   // elements per packed matrix
constexpr int XP = 132;            // padded LDS row stride (floats)
}

typedef __attribute__((ext_vector_type(8))) short short8v;
typedef __attribute__((ext_vector_type(4))) float f32x4;

__device__ __forceinline__ unsigned short bf16rne(float f) {
    unsigned u = __float_as_uint(f);
    unsigned r = (u + 0x7fffu + ((u >> 16) & 1u)) >> 16;
    return (unsigned short)r;
}
__device__ __forceinline__ float bf16f(unsigned short h) {
    return __uint_as_float(((unsigned)h) << 16);
}

// cw layout: [which(2)][type(4)][row(129)][col(128)]; row 128 = transformed bias
__global__ void build_cw_kernel(const float* __restrict__ Wk, const float* __restrict__ bk,
                                const float* __restrict__ Wv, const float* __restrict__ bv,
                                const float* __restrict__ a_rel, const float* __restrict__ m_rel,
                                float* __restrict__ cw)
{
    const int total = 2 * 4 * 129 * 128;
    int idx = blockIdx.x * blockDim.x + threadIdx.x;
    if (idx >= total) return;
    int c     = idx & 127;
    int r     = (idx >> 7) % 129;
    int t     = ((idx >> 7) / 129) & 3;
    int which = idx / (4 * 129 * 128);
    const int et_map[4] = {2, 3, 0, 1};
    int et = et_map[t];
    const float* W = (which == 0 ? Wk : Wv) + (size_t)t * HIDN * HIDN;
    const float* b = (which == 0 ? bk : bv) + (size_t)t * HIDN;
    const float* A = (which == 0 ? a_rel : m_rel) + (size_t)et * NHEAD * DHEAD * DHEAD;
    int h = c >> 4, e2 = c & 15;
    float s = 0.f;
#pragma unroll
    for (int d = 0; d < DHEAD; ++d) {
        float w = (r == 128) ? b[h * DHEAD + d] : W[(size_t)r * HIDN + h * DHEAD + d];
        s = fmaf(w, A[h * DHEAD * DHEAD + d * DHEAD + e2], s);
    }
    cw[idx] = s;
}

// Pack 12 matrices into MFMA B-fragment order (bf16 hi/lo) + fp32 bias table.
// Fragment index: ((ks*8+ct)*64 + lane)*8 + i ; logical k = ks*32 + (lane>>4)*8 + i,
// col = ct*16 + (lane&15). A-side uses the SAME mapping => k-permutation cancels.
__global__ void pack_kernel(const float* __restrict__ cw,
                            const float* __restrict__ Wq, const float* __restrict__ bq,
                            const float* __restrict__ Wo, const float* __restrict__ bo,
                            short* __restrict__ pkh, short* __restrict__ pkl,
                            float* __restrict__ bias)
{
    const int total = NMAT * MATSZ + NMAT * HIDN;
    int idx = blockIdx.x * blockDim.x + threadIdx.x;
    if (idx >= total) return;
    if (idx < NMAT * MATSZ) {
        int mat = idx >> 14;
        int rem = idx & (MATSZ - 1);
        int i    = rem & 7;
        int lane = (rem >> 3) & 63;
        int ct   = (rem >> 9) & 7;
        int ks   = rem >> 12;
        int k   = ks * 32 + ((lane >> 4) & 3) * 8 + i;
        int col = ct * 16 + (lane & 15);
        float v;
        if (mat < 8)       v = cw[(size_t)mat * 129 * 128 + (size_t)k * 128 + col];
        else if (mat < 10) v = Wq[(size_t)(mat - 8) * MATSZ + (size_t)k * 128 + col];
        else               v = Wo[(size_t)(mat - 10) * MATSZ + (size_t)k * 128 + col];
        unsigned short hb = bf16rne(v);
        float rest = v - bf16f(hb);
        pkh[idx] = (short)hb;
        pkl[idx] = (short)bf16rne(rest);
    } else {
        int b = idx - NMAT * MATSZ;
        int mat = b >> 7, col = b & 127;
        float v;
        if (mat < 8)       v = cw[(size_t)mat * 129 * 128 + (size_t)128 * 128 + col];
        else if (mat < 10) v = bq[(mat - 8) * HIDN + col];
        else               v = bo[(mat - 10) * HIDN + col];
        bias[b] = v;
    }
}

// Split-bf16 MFMA GEMM: d[M][128] = x[M][128] @ W_mat + bias_mat, NM matrices
// sharing the staged x tile. 256 threads, 64-row tile, wave w owns rows w*16..+15.
template<int NM>
__global__ __launch_bounds__(256) void mfma_proj_kernel(
    const float* __restrict__ x, int M,
    const short* __restrict__ pkh, const short* __restrict__ pkl,
    const float* __restrict__ bias,
    int m0, int m1, int m2,
    float* __restrict__ d0, float* __restrict__ d1, float* __restrict__ d2)
{
    __shared__ float xs[64 * XP];
    const int t  = threadIdx.x;
    const int r0 = blockIdx.x * 64;
    const int rows = min(64, M - r0);

#pragma unroll
    for (int p = 0; p < 8; ++p) {
        int f = p * 256 + t;          // 2048 float4 slots
        int row = f >> 5, c4 = f & 31;
        float4 v = make_float4(0.f, 0.f, 0.f, 0.f);
        if (row < rows) v = *(const float4*)(x + (size_t)(r0 + row) * HIDN + c4 * 4);
        *(float4*)&xs[row * XP + c4 * 4] = v;
    }
    __syncthreads();

    const int l = t & 63, w = t >> 6;
    const int arow = w * 16 + (l & 15);
    const int kgrp = l >> 4;

    short8v ahi[4], alo[4];
#pragma unroll
    for (int ks = 0; ks < 4; ++ks) {
        const float* xp = &xs[arow * XP + ks * 32 + kgrp * 8];
        float4 va = *(const float4*)xp;
        float4 vb = *(const float4*)(xp + 4);
        float vv[8] = {va.x, va.y, va.z, va.w, vb.x, vb.y, vb.z, vb.w};
#pragma unroll
        for (int i = 0; i < 8; ++i) {
            unsigned short hb = bf16rne(vv[i]);
            ahi[ks][i] = (short)hb;
            alo[ks][i] = (short)bf16rne(vv[i] - bf16f(hb));
        }
    }

    for (int mi = 0; mi < NM; ++mi) {
        const int mat = (mi == 0) ? m0 : (mi == 1) ? m1 : m2;
        float* dst    = (mi == 0) ? d0 : (mi == 1) ? d1 : d2;
        const short8v* bh = (const short8v*)(pkh + (size_t)mat * MATSZ);
        const short8v* bl = (const short8v*)(pkl + (size_t)mat * MATSZ);
        const float*   bs = bias + mat * HIDN;

        f32x4 acc[8];
        f32x4 z; z[0] = 0.f; z[1] = 0.f; z[2] = 0.f; z[3] = 0.f;
#pragma unroll
        for (int ct = 0; ct < 8; ++ct) acc[ct] = z;

#pragma unroll
        for (int ct = 0; ct < 8; ++ct) {
#pragma unroll
            for (int ks = 0; ks < 4; ++ks) {
                short8v b1 = bh[(ks * 8 + ct) * 64 + l];
                short8v b2 = bl[(ks * 8 + ct) * 64 + l];
                acc[ct] = __builtin_amdgcn_mfma_f32_16x16x32_bf16(ahi[ks], b1, acc[ct], 0, 0, 0);
                acc[ct] = __builtin_amdgcn_mfma_f32_16x16x32_bf16(alo[ks], b1, acc[ct], 0, 0, 0);
                acc[ct] = __builtin_amdgcn_mfma_f32_16x16x32_bf16(ahi[ks], b2, acc[ct], 0, 0, 0);
            }
        }

        const int crow0 = w * 16 + kgrp * 4;
        const int ccol  = l & 15;
#pragma unroll
        for (int ct = 0; ct < 8; ++ct) {
            float bv = bs[ct * 16 + ccol];
#pragma unroll
            for (int j = 0; j < 4; ++j) {
                int grow = r0 + crow0 + j;
                if (grow < M)
                    dst[(size_t)grow * HIDN + ct * 16 + ccol] = acc[ct][j] + bv;
            }
        }
    }
}

// Epilogue: out = gate*(gelu(agg) @ Wo + bo) + (1-gate)*xin
__global__ __launch_bounds__(256) void mfma_out_kernel(
    const float* __restrict__ agg, int M,
    const short* __restrict__ pkh, const short* __restrict__ pkl,
    const float* __restrict__ bias, int mat,
    const float* __restrict__ xin, const float* __restrict__ skip_ptr,
    float* __restrict__ out)
{
    __shared__ float xs[64 * XP];
    const int t  = threadIdx.x;
    const int r0 = blockIdx.x * 64;
    const int rows = min(64, M - r0);

#pragma unroll
    for (int p = 0; p < 8; ++p) {
        int f = p * 256 + t;
        int row = f >> 5, c4 = f & 31;
        float4 v = make_float4(0.f, 0.f, 0.f, 0.f);
        if (row < rows) v = *(const float4*)(agg + (size_t)(r0 + row) * HIDN + c4 * 4);
        *(float4*)&xs[row * XP + c4 * 4] = v;
    }
    __syncthreads();

    const int l = t & 63, w = t >> 6;
    const int arow = w * 16 + (l & 15);
    const int kgrp = l >> 4;

    short8v ahi[4], alo[4];
#pragma unroll
    for (int ks = 0; ks < 4; ++ks) {
        const float* xp = &xs[arow * XP + ks * 32 + kgrp * 8];
        float4 va = *(const float4*)xp;
        float4 vb = *(const float4*)(xp + 4);
        float vv[8] = {va.x, va.y, va.z, va.w, vb.x, vb.y, vb.z, vb.w};
#pragma unroll
        for (int i = 0; i < 8; ++i) {
            float g = 0.5f * vv[i] * (1.0f + erff(vv[i] * 0.70710678118654752440f));
            unsigned short hb = bf16rne(g);
            ahi[ks][i] = (short)hb;
            alo[ks][i] = (short)bf16rne(g - bf16f(hb));
        }
    }

    const short8v* bh = (const short8v*)(pkh + (size_t)mat * MATSZ);
    const short8v* bl = (const short8v*)(pkl + (size_t)mat * MATSZ);
    const float*   bs = bias + mat * HIDN;

    f32x4 acc[8];
    f32x4 z; z[0] = 0.f; z[1] = 0.f; z[2] = 0.f; z[3] = 0.f;
#pragma unroll
    for (int ct = 0; ct < 8; ++ct) acc[ct] = z;

#pragma unroll
    for (int ct = 0; ct < 8; ++ct) {
#pragma unroll
        for (int ks = 0; ks < 4; ++ks) {
            short8v b1 = bh[(ks * 8 + ct) * 64 + l];
            short8v b2 = bl[(ks * 8 + ct) * 64 + l];
            acc[ct] = __builtin_amdgcn_mfma_f32_16x16x32_bf16(ahi[ks], b1, acc[ct], 0, 0, 0);
            acc[ct] = __builtin_amdgcn_mfma_f32_16x16x32_bf16(alo[ks], b1, acc[ct], 0, 0, 0);
            acc[ct] = __builtin_amdgcn_mfma_f32_16x16x32_bf16(ahi[ks], b2, acc[ct], 0, 0, 0);
        }
    }

    const float gate = 1.f / (1.f + expf(-skip_ptr[0]));
    const int crow0 = w * 16 + kgrp * 4;
    const int ccol  = l & 15;
#pragma unroll
    for (int ct = 0; ct < 8; ++ct) {
        float bv = bs[ct * 16 + ccol];
#pragma unroll
        for (int j = 0; j < 4; ++j) {
            int grow = r0 + crow0 + j;
            if (grow < M) {
                size_t o = (size_t)grow * HIDN + ct * 16 + ccol;
                out[o] = gate * (acc[ct][j] + bv) + (1.f - gate) * xin[o];
            }
        }
    }
}

__device__ __forceinline__ unsigned float_order_key(float f) {
    unsigned u = __float_as_uint(f);
    return (u & 0x80000000u) ? ~u : (u | 0x80000000u);
}
__device__ __forceinline__ float float_order_unkey(unsigned u) {
    return (u & 0x80000000u) ? __uint_as_float(u ^ 0x80000000u) : __uint_as_float(~u);
}

// Pass A: alpha per (edge, head); store alpha; atomicMax per (dst, head).
__global__ void edge_alpha_kernel(const int* __restrict__ src, const int* __restrict__ dst, int E,
                                  const float* __restrict__ kr, const float* __restrict__ q,
                                  const float* __restrict__ prow,
                                  float* __restrict__ exbuf, unsigned* __restrict__ amax)
{
    int idx = blockIdx.x * blockDim.x + threadIdx.x;
    if (idx >= E * NHEAD) return;
    int e = idx >> 3, h = idx & 7;
    int s = src[e], d = dst[e];
    const float4* qp = (const float4*)(q  + (size_t)d * HIDN + h * DHEAD);
    const float4* kp = (const float4*)(kr + (size_t)s * HIDN + h * DHEAD);
    float acc = 0.f;
#pragma unroll
    for (int i = 0; i < 4; ++i) {
        float4 a4 = qp[i], b4 = kp[i];
        acc += a4.x * b4.x + a4.y * b4.y + a4.z * b4.z + a4.w * b4.w;
    }
    float alpha = acc * prow[h] * 0.25f;   // 1/sqrt(16)
    exbuf[idx] = alpha;
    atomicMax(amax + (size_t)d * NHEAD + h, float_order_key(alpha));
}

// Pass B: ex = exp(alpha - max); overwrite exbuf; atomicAdd denom.
__global__ void edge_expden_kernel(const int* __restrict__ dst, int E,
                                   const unsigned* __restrict__ amax,
                                   float* __restrict__ exbuf, float* __restrict__ den)
{
    int idx = blockIdx.x * blockDim.x + threadIdx.x;
    if (idx >= E * NHEAD) return;
    int e = idx >> 3, h = idx & 7;
    int d = dst[e];
    float m  = float_order_unkey(amax[(size_t)d * NHEAD + h]);
    float ex = expf(exbuf[idx] - m);
    exbuf[idx] = ex;
    atomicAdd(den + (size_t)d * NHEAD + h, ex);
}

// Pass C: agg[dst] += (ex/den) * vr[src]; 128 consecutive threads per edge.
__global__ void edge_agg_kernel(const int* __restrict__ src, const int* __restrict__ dst, int E,
                                const float* __restrict__ vr, const float* __restrict__ exbuf,
                                const float* __restrict__ den, float* __restrict__ agg)
{
    long long idx = (long long)blockIdx.x * blockDim.x + threadIdx.x;
    if (idx >= (long long)E * HIDN) return;
    int e = (int)(idx >> 7);
    int j = (int)(idx & 127);
    int h = j >> 4;
    int s = src[e], d = dst[e];
    float w = exbuf[(size_t)e * NHEAD + h] / (den[(size_t)d * NHEAD + h] + 1e-16f);
    atomicAdd(agg + (size_t)d * HIDN + j, w * vr[(size_t)s * HIDN + j]);
}

extern "C" void kernel_launch(void* const* d_in, const int* in_sizes, int n_in,
                              void* d_out, int out_size, void* d_ws, size_t ws_size,
                              hipStream_t stream)
{
    const float* x_user = (const float*)d_in[0];
    const float* x_item = (const float*)d_in[1];
    const float* x_taste= (const float*)d_in[2];
    const float* x_image= (const float*)d_in[3];
    const float* Wk     = (const float*)d_in[4];
    const float* bk     = (const float*)d_in[5];
    const float* Wq     = (const float*)d_in[6];
    const float* bq     = (const float*)d_in[7];
    const float* Wv     = (const float*)d_in[8];
    const float* bv     = (const float*)d_in[9];
    const float* a_rel  = (const float*)d_in[10];
    const float* m_rel  = (const float*)d_in[11];
    const float* p_rel  = (const float*)d_in[12];
    const float* Wo     = (const float*)d_in[13];
    const float* bo     = (const float*)d_in[14];
    const float* skip   = (const float*)d_in[15];
    const int* ti_src = (const int*)d_in[16];
    const int* ti_dst = (const int*)d_in[17];
    const int* im_src = (const int*)d_in[18];
    const int* im_dst = (const int*)d_in[19];
    const int* ub_src = (const int*)d_in[20];
    const int* ub_dst = (const int*)d_in[21];
    const int* bu_src = (const int*)d_in[22];
    const int* bu_dst = (const int*)d_in[23];

    float* ws = (float*)d_ws;
    float* outp = (float*)d_out;
    (void)in_sizes; (void)n_in; (void)out_size;

    // ---- workspace layout (floats) ----
    size_t off = 0;
    auto alloc = [&](size_t n) { size_t o = off; off += n; return o; };
    const size_t o_cwk  = alloc((size_t)2 * 4 * 129 * 128);        // fp32 combined k/v weights
    const size_t o_pkh  = alloc((size_t)NMAT * MATSZ / 2);         // bf16 hi (shorts)
    const size_t o_pkl  = alloc((size_t)NMAT * MATSZ / 2);         // bf16 lo (shorts)
    const size_t o_bias = alloc((size_t)NMAT * HIDN);
    // kr region: [kr_u | kr_i | kr_t | kr_g]; REUSED as [agg_i | agg_u] after pass A
    const size_t o_kr   = alloc((size_t)(NU + NI + NT + NG) * HIDN);
    const size_t o_kr_u = o_kr;
    const size_t o_kr_i = o_kr_u + (size_t)NU * HIDN;
    const size_t o_kr_t = o_kr_i + (size_t)NI * HIDN;
    const size_t o_kr_g = o_kr_t + (size_t)NT * HIDN;
    const size_t o_vr   = alloc((size_t)(NU + NI + NT + NG) * HIDN);
    const size_t o_vr_u = o_vr;
    const size_t o_vr_i = o_vr_u + (size_t)NU * HIDN;
    const size_t o_vr_t = o_vr_i + (size_t)NI * HIDN;
    const size_t o_vr_g = o_vr_t + (size_t)NT * HIDN;
    const size_t o_q_i  = alloc((size_t)NI * HIDN);
    const size_t o_q_u  = alloc((size_t)NU * HIDN);
    // zero region: amax + den
    const size_t o_zero1  = off;
    const size_t o_amax_i = alloc((size_t)NI * NHEAD);
    const size_t o_amax_u = alloc((size_t)NU * NHEAD);
    const size_t o_den_i  = alloc((size_t)NI * NHEAD);
    const size_t o_den_u  = alloc((size_t)NU * NHEAD);
    const size_t zero1_bytes = (off - o_zero1) * sizeof(float);

    if (ws_size < off * sizeof(float)) return;  // clean failure instead of OOB fault

    // exp-buffer lives in d_out; agg reuses kr region
    const size_t o_agg_i = o_kr;
    const size_t o_agg_u = o_kr + (size_t)NI * HIDN;
    float* ex_i = outp;
    float* ex_u = outp + (size_t)(E_TI + E_IM + E_UB) * NHEAD;
    const size_t agg_bytes = (size_t)(NI + NU) * HIDN * sizeof(float);

    short* pkh  = (short*)(ws + o_pkh);
    short* pkl  = (short*)(ws + o_pkl);
    float* bias = ws + o_bias;

    // ---- 1. combined relation-fused weights + MFMA pack ----
    {
        int total = 2 * 4 * 129 * 128;
        build_cw_kernel<<<(total + 255) / 256, 256, 0, stream>>>(
            Wk, bk, Wv, bv, a_rel, m_rel, ws + o_cwk);
        int ptotal = NMAT * MATSZ + NMAT * HIDN;
        pack_kernel<<<(ptotal + 255) / 256, 256, 0, stream>>>(
            ws + o_cwk, Wq, bq, Wo, bo, pkh, pkl, bias);
    }

    hipMemsetAsync(ws + o_zero1, 0, zero1_bytes, stream);

    // ---- 2. split-bf16 MFMA projections ----
    // mats: k=type, v=4+type, q: 8(user) 9(item)
    mfma_proj_kernel<3><<<(NU + 63) / 64, 256, 0, stream>>>(
        x_user, NU, pkh, pkl, bias, 0, 4, 8,
        ws + o_kr_u, ws + o_vr_u, ws + o_q_u);
    mfma_proj_kernel<3><<<(NI + 63) / 64, 256, 0, stream>>>(
        x_item, NI, pkh, pkl, bias, 1, 5, 9,
        ws + o_kr_i, ws + o_vr_i, ws + o_q_i);
    mfma_proj_kernel<2><<<(NT + 63) / 64, 256, 0, stream>>>(
        x_taste, NT, pkh, pkl, bias, 2, 6, 0,
        ws + o_kr_t, ws + o_vr_t, nullptr);
    mfma_proj_kernel<2><<<(NG + 63) / 64, 256, 0, stream>>>(
        x_image, NG, pkh, pkl, bias, 3, 7, 0,
        ws + o_kr_g, ws + o_vr_g, nullptr);

    // ---- 3. pass A: alpha + segment max (ex written into d_out) ----
    auto launchA = [&](const int* s, const int* d, int E, size_t o_kr_, size_t o_q_,
                       int et, float* ex, size_t o_amax) {
        int n = E * NHEAD;
        edge_alpha_kernel<<<(n + 255) / 256, 256, 0, stream>>>(
            s, d, E, ws + o_kr_, ws + o_q_, p_rel + et * NHEAD,
            ex, (unsigned*)(ws + o_amax));
    };
    launchA(ti_src, ti_dst, E_TI, o_kr_t, o_q_i, 0, ex_i,                                 o_amax_i);
    launchA(im_src, im_dst, E_IM, o_kr_g, o_q_i, 1, ex_i + (size_t)E_TI * NHEAD,          o_amax_i);
    launchA(ub_src, ub_dst, E_UB, o_kr_u, o_q_i, 2, ex_i + (size_t)(E_TI + E_IM) * NHEAD, o_amax_i);
    launchA(bu_src, bu_dst, E_BU, o_kr_i, o_q_u, 3, ex_u,                                 o_amax_u);

    // zero agg (kr region dead after pass A; stream order guarantees safety)
    hipMemsetAsync(ws + o_agg_i, 0, agg_bytes, stream);

    // ---- 4. pass B: exp + denom ----
    auto launchB = [&](const int* d, int E, float* ex, size_t o_amax, size_t o_den) {
        int n = E * NHEAD;
        edge_expden_kernel<<<(n + 255) / 256, 256, 0, stream>>>(
            d, E, (const unsigned*)(ws + o_amax), ex, ws + o_den);
    };
    launchB(ti_dst, E_TI, ex_i,                                 o_amax_i, o_den_i);
    launchB(im_dst, E_IM, ex_i + (size_t)E_TI * NHEAD,          o_amax_i, o_den_i);
    launchB(ub_dst, E_UB, ex_i + (size_t)(E_TI + E_IM) * NHEAD, o_amax_i, o_den_i);
    launchB(bu_dst, E_BU, ex_u,                                 o_amax_u, o_den_u);

    // ---- 5. pass C: weighted scatter-add of messages ----
    auto launchC = [&](const int* s, const int* d, int E, size_t o_vr_,
                       const float* ex, size_t o_den, size_t o_agg) {
        long long n = (long long)E * HIDN;
        edge_agg_kernel<<<(unsigned)((n + 255) / 256), 256, 0, stream>>>(
            s, d, E, ws + o_vr_, ex, ws + o_den, ws + o_agg);
    };
    launchC(ti_src, ti_dst, E_TI, o_vr_t, ex_i,                                 o_den_i, o_agg_i);
    launchC(im_src, im_dst, E_IM, o_vr_g, ex_i + (size_t)E_TI * NHEAD,          o_den_i, o_agg_i);
    launchC(ub_src, ub_dst, E_UB, o_vr_u, ex_i + (size_t)(E_TI + E_IM) * NHEAD, o_den_i, o_agg_i);
    launchC(bu_src, bu_dst, E_BU, o_vr_i, ex_u,                                 o_den_u, o_agg_u);

    // ---- 6. epilogue GEMMs (split-bf16 MFMA, gelu-in, gated blend out) ----
    mfma_out_kernel<<<(NI + 63) / 64, 256, 0, stream>>>(
        ws + o_agg_i, NI, pkh, pkl, bias, 10, x_item, skip + 0, outp);
    mfma_out_kernel<<<(NU + 63) / 64, 256, 0, stream>>>(
        ws + o_agg_u, NU, pkh, pkl, bias, 11, x_user, skip + 1,
        outp + (size_t)NI * HIDN);
}

// Round 4
// 804.854 us; speedup vs baseline: 1.6651x; 1.3177x over previous
//
#include <hip/hip_runtime.h>
#include <math.h>

// ---------------------------------------------------------------------------
// MultiModalFusionGAT — round 4
//   Projections/epilogue: split-bf16 MFMA (unchanged from round 3).
//   Edge softmax-aggregation: atomic-free. On-device CSR by dst
//   (histogram -> hierarchical scan -> scatter), then two gather kernels:
//     F1: alpha + per-head max + exp   (scratch in d_out)
//     F2: weighted gather-sum + normalize, single coalesced agg write
// ---------------------------------------------------------------------------

namespace {
constexpr int HIDN  = 128;
constexpr int NHEAD = 8;

constexpr int NU = 20000, NI = 50000, NT = 50000, NG = 50000;
constexpr int E_TI = 50000, E_IM = 50000, E_UB = 500000, E_BU = 500000;
constexpr int ETOT = E_TI + E_IM + E_UB + E_BU;   // 1,100,000
constexpr int ND   = NI + NU;                     // dst nodes: items then users

// src row bases in the combined kr/vr table [user | item | taste | image]
constexpr int BASE_U = 0;
constexpr int BASE_I = NU;
constexpr int BASE_T = NU + NI;
constexpr int BASE_G = NU + NI + NT;

constexpr int NMAT = 12;           // 0..3 k, 4..7 v, 8/9 q(user,item), 10/11 Wo(item,user)
constexpr int MATSZ = 128 * 128;
constexpr int XP = 132;            // padded LDS row stride (floats)
}

typedef __attribute__((ext_vector_type(8))) short short8v;
typedef __attribute__((ext_vector_type(4))) float f32x4;

__device__ __forceinline__ unsigned short bf16rne(float f) {
    unsigned u = __float_as_uint(f);
    unsigned r = (u + 0x7fffu + ((u >> 16) & 1u)) >> 16;
    return (unsigned short)r;
}
__device__ __forceinline__ float bf16f(unsigned short h) {
    return __uint_as_float(((unsigned)h) << 16);
}

// cw layout: [which(2)][type(4)][row(129)][col(128)]; row 128 = transformed bias
__global__ void build_cw_kernel(const float* __restrict__ Wk, const float* __restrict__ bk,
                                const float* __restrict__ Wv, const float* __restrict__ bv,
                                const float* __restrict__ a_rel, const float* __restrict__ m_rel,
                                float* __restrict__ cw)
{
    const int total = 2 * 4 * 129 * 128;
    int idx = blockIdx.x * blockDim.x + threadIdx.x;
    if (idx >= total) return;
    int c     = idx & 127;
    int r     = (idx >> 7) % 129;
    int t     = ((idx >> 7) / 129) & 3;
    int which = idx / (4 * 129 * 128);
    const int et_map[4] = {2, 3, 0, 1};
    int et = et_map[t];
    const float* W = (which == 0 ? Wk : Wv) + (size_t)t * HIDN * HIDN;
    const float* b = (which == 0 ? bk : bv) + (size_t)t * HIDN;
    const float* A = (which == 0 ? a_rel : m_rel) + (size_t)et * NHEAD * 16 * 16;
    int h = c >> 4, e2 = c & 15;
    float s = 0.f;
#pragma unroll
    for (int d = 0; d < 16; ++d) {
        float w = (r == 128) ? b[h * 16 + d] : W[(size_t)r * HIDN + h * 16 + d];
        s = fmaf(w, A[h * 256 + d * 16 + e2], s);
    }
    cw[idx] = s;
}

// Pack 12 matrices into MFMA B-fragment order (bf16 hi/lo) + fp32 bias table.
__global__ void pack_kernel(const float* __restrict__ cw,
                            const float* __restrict__ Wq, const float* __restrict__ bq,
                            const float* __restrict__ Wo, const float* __restrict__ bo,
                            short* __restrict__ pkh, short* __restrict__ pkl,
                            float* __restrict__ bias)
{
    const int total = NMAT * MATSZ + NMAT * HIDN;
    int idx = blockIdx.x * blockDim.x + threadIdx.x;
    if (idx >= total) return;
    if (idx < NMAT * MATSZ) {
        int mat = idx >> 14;
        int rem = idx & (MATSZ - 1);
        int i    = rem & 7;
        int lane = (rem >> 3) & 63;
        int ct   = (rem >> 9) & 7;
        int ks   = rem >> 12;
        int k   = ks * 32 + ((lane >> 4) & 3) * 8 + i;
        int col = ct * 16 + (lane & 15);
        float v;
        if (mat < 8)       v = cw[(size_t)mat * 129 * 128 + (size_t)k * 128 + col];
        else if (mat < 10) v = Wq[(size_t)(mat - 8) * MATSZ + (size_t)k * 128 + col];
        else               v = Wo[(size_t)(mat - 10) * MATSZ + (size_t)k * 128 + col];
        unsigned short hb = bf16rne(v);
        float rest = v - bf16f(hb);
        pkh[idx] = (short)hb;
        pkl[idx] = (short)bf16rne(rest);
    } else {
        int b = idx - NMAT * MATSZ;
        int mat = b >> 7, col = b & 127;
        float v;
        if (mat < 8)       v = cw[(size_t)mat * 129 * 128 + (size_t)128 * 128 + col];
        else if (mat < 10) v = bq[(mat - 8) * HIDN + col];
        else               v = bo[(mat - 10) * HIDN + col];
        bias[b] = v;
    }
}

// Split-bf16 MFMA GEMM: d[M][128] = x[M][128] @ W_mat + bias_mat
template<int NM>
__global__ __launch_bounds__(256) void mfma_proj_kernel(
    const float* __restrict__ x, int M,
    const short* __restrict__ pkh, const short* __restrict__ pkl,
    const float* __restrict__ bias,
    int m0, int m1, int m2,
    float* __restrict__ d0, float* __restrict__ d1, float* __restrict__ d2)
{
    __shared__ float xs[64 * XP];
    const int t  = threadIdx.x;
    const int r0 = blockIdx.x * 64;
    const int rows = min(64, M - r0);

#pragma unroll
    for (int p = 0; p < 8; ++p) {
        int f = p * 256 + t;
        int row = f >> 5, c4 = f & 31;
        float4 v = make_float4(0.f, 0.f, 0.f, 0.f);
        if (row < rows) v = *(const float4*)(x + (size_t)(r0 + row) * HIDN + c4 * 4);
        *(float4*)&xs[row * XP + c4 * 4] = v;
    }
    __syncthreads();

    const int l = t & 63, w = t >> 6;
    const int arow = w * 16 + (l & 15);
    const int kgrp = l >> 4;

    short8v ahi[4], alo[4];
#pragma unroll
    for (int ks = 0; ks < 4; ++ks) {
        const float* xp = &xs[arow * XP + ks * 32 + kgrp * 8];
        float4 va = *(const float4*)xp;
        float4 vb = *(const float4*)(xp + 4);
        float vv[8] = {va.x, va.y, va.z, va.w, vb.x, vb.y, vb.z, vb.w};
#pragma unroll
        for (int i = 0; i < 8; ++i) {
            unsigned short hb = bf16rne(vv[i]);
            ahi[ks][i] = (short)hb;
            alo[ks][i] = (short)bf16rne(vv[i] - bf16f(hb));
        }
    }

    for (int mi = 0; mi < NM; ++mi) {
        const int mat = (mi == 0) ? m0 : (mi == 1) ? m1 : m2;
        float* dst    = (mi == 0) ? d0 : (mi == 1) ? d1 : d2;
        const short8v* bh = (const short8v*)(pkh + (size_t)mat * MATSZ);
        const short8v* bl = (const short8v*)(pkl + (size_t)mat * MATSZ);
        const float*   bs = bias + mat * HIDN;

        f32x4 acc[8];
        f32x4 z; z[0] = 0.f; z[1] = 0.f; z[2] = 0.f; z[3] = 0.f;
#pragma unroll
        for (int ct = 0; ct < 8; ++ct) acc[ct] = z;

#pragma unroll
        for (int ct = 0; ct < 8; ++ct) {
#pragma unroll
            for (int ks = 0; ks < 4; ++ks) {
                short8v b1 = bh[(ks * 8 + ct) * 64 + l];
                short8v b2 = bl[(ks * 8 + ct) * 64 + l];
                acc[ct] = __builtin_amdgcn_mfma_f32_16x16x32_bf16(ahi[ks], b1, acc[ct], 0, 0, 0);
                acc[ct] = __builtin_amdgcn_mfma_f32_16x16x32_bf16(alo[ks], b1, acc[ct], 0, 0, 0);
                acc[ct] = __builtin_amdgcn_mfma_f32_16x16x32_bf16(ahi[ks], b2, acc[ct], 0, 0, 0);
            }
        }

        const int crow0 = w * 16 + kgrp * 4;
        const int ccol  = l & 15;
#pragma unroll
        for (int ct = 0; ct < 8; ++ct) {
            float bv = bs[ct * 16 + ccol];
#pragma unroll
            for (int j = 0; j < 4; ++j) {
                int grow = r0 + crow0 + j;
                if (grow < M)
                    dst[(size_t)grow * HIDN + ct * 16 + ccol] = acc[ct][j] + bv;
            }
        }
    }
}

// Epilogue: out = gate*(gelu(agg) @ Wo + bo) + (1-gate)*xin
__global__ __launch_bounds__(256) void mfma_out_kernel(
    const float* __restrict__ agg, int M,
    const short* __restrict__ pkh, const short* __restrict__ pkl,
    const float* __restrict__ bias, int mat,
    const float* __restrict__ xin, const float* __restrict__ skip_ptr,
    float* __restrict__ out)
{
    __shared__ float xs[64 * XP];
    const int t  = threadIdx.x;
    const int r0 = blockIdx.x * 64;
    const int rows = min(64, M - r0);

#pragma unroll
    for (int p = 0; p < 8; ++p) {
        int f = p * 256 + t;
        int row = f >> 5, c4 = f & 31;
        float4 v = make_float4(0.f, 0.f, 0.f, 0.f);
        if (row < rows) v = *(const float4*)(agg + (size_t)(r0 + row) * HIDN + c4 * 4);
        *(float4*)&xs[row * XP + c4 * 4] = v;
    }
    __syncthreads();

    const int l = t & 63, w = t >> 6;
    const int arow = w * 16 + (l & 15);
    const int kgrp = l >> 4;

    short8v ahi[4], alo[4];
#pragma unroll
    for (int ks = 0; ks < 4; ++ks) {
        const float* xp = &xs[arow * XP + ks * 32 + kgrp * 8];
        float4 va = *(const float4*)xp;
        float4 vb = *(const float4*)(xp + 4);
        float vv[8] = {va.x, va.y, va.z, va.w, vb.x, vb.y, vb.z, vb.w};
#pragma unroll
        for (int i = 0; i < 8; ++i) {
            float g = 0.5f * vv[i] * (1.0f + erff(vv[i] * 0.70710678118654752440f));
            unsigned short hb = bf16rne(g);
            ahi[ks][i] = (short)hb;
            alo[ks][i] = (short)bf16rne(g - bf16f(hb));
        }
    }

    const short8v* bh = (const short8v*)(pkh + (size_t)mat * MATSZ);
    const short8v* bl = (const short8v*)(pkl + (size_t)mat * MATSZ);
    const float*   bs = bias + mat * HIDN;

    f32x4 acc[8];
    f32x4 z; z[0] = 0.f; z[1] = 0.f; z[2] = 0.f; z[3] = 0.f;
#pragma unroll
    for (int ct = 0; ct < 8; ++ct) acc[ct] = z;

#pragma unroll
    for (int ct = 0; ct < 8; ++ct) {
#pragma unroll
        for (int ks = 0; ks < 4; ++ks) {
            short8v b1 = bh[(ks * 8 + ct) * 64 + l];
            short8v b2 = bl[(ks * 8 + ct) * 64 + l];
            acc[ct] = __builtin_amdgcn_mfma_f32_16x16x32_bf16(ahi[ks], b1, acc[ct], 0, 0, 0);
            acc[ct] = __builtin_amdgcn_mfma_f32_16x16x32_bf16(alo[ks], b1, acc[ct], 0, 0, 0);
            acc[ct] = __builtin_amdgcn_mfma_f32_16x16x32_bf16(ahi[ks], b2, acc[ct], 0, 0, 0);
        }
    }

    const float gate = 1.f / (1.f + expf(-skip_ptr[0]));
    const int crow0 = w * 16 + kgrp * 4;
    const int ccol  = l & 15;
#pragma unroll
    for (int ct = 0; ct < 8; ++ct) {
        float bv = bs[ct * 16 + ccol];
#pragma unroll
        for (int j = 0; j < 4; ++j) {
            int grow = r0 + crow0 + j;
            if (grow < M) {
                size_t o = (size_t)grow * HIDN + ct * 16 + ccol;
                out[o] = gate * (acc[ct][j] + bv) + (1.f - gate) * xin[o];
            }
        }
    }
}

// ----------------------- CSR construction -----------------------

__global__ void hist_kernel(const int* __restrict__ ti_dst, const int* __restrict__ im_dst,
                            const int* __restrict__ ub_dst, const int* __restrict__ bu_dst,
                            int* __restrict__ deg)
{
    int i = blockIdx.x * blockDim.x + threadIdx.x;
    if (i >= ETOT) return;
    int d;
    if (i < E_TI)                     d = ti_dst[i];
    else if (i < E_TI + E_IM)         d = im_dst[i - E_TI];
    else if (i < E_TI + E_IM + E_UB)  d = ub_dst[i - E_TI - E_IM];
    else                              d = NI + bu_dst[i - E_TI - E_IM - E_UB];
    atomicAdd(&deg[d], 1);
}

// in-place inclusive scan of 256-chunks; chunk totals -> tops
__global__ void scan1_kernel(int* __restrict__ deg, int* __restrict__ tops, int n)
{
    __shared__ int sh[256];
    int i = blockIdx.x * 256 + threadIdx.x;
    int v = (i < n) ? deg[i] : 0;
    sh[threadIdx.x] = v;
    __syncthreads();
    for (int o = 1; o < 256; o <<= 1) {
        int t = (threadIdx.x >= o) ? sh[threadIdx.x - o] : 0;
        __syncthreads();
        sh[threadIdx.x] += t;
        __syncthreads();
    }
    if (i < n) deg[i] = sh[threadIdx.x];
    if (threadIdx.x == 255) tops[blockIdx.x] = sh[255];
}

__global__ void scan2_kernel(int* __restrict__ tops, int nb)
{
    __shared__ int sh[1024];
    int v = (threadIdx.x < nb) ? tops[threadIdx.x] : 0;
    sh[threadIdx.x] = v;
    __syncthreads();
    for (int o = 1; o < 1024; o <<= 1) {
        int t = (threadIdx.x >= o) ? sh[threadIdx.x - o] : 0;
        __syncthreads();
        sh[threadIdx.x] += t;
        __syncthreads();
    }
    if (threadIdx.x < nb) tops[threadIdx.x] = sh[threadIdx.x];
}

__global__ void scan3_kernel(const int* __restrict__ part, const int* __restrict__ tops,
                             int* __restrict__ rowptr, int n)
{
    int i = blockIdx.x * 256 + threadIdx.x;
    if (i >= n) return;
    int add = (blockIdx.x > 0) ? tops[blockIdx.x - 1] : 0;
    rowptr[i + 1] = part[i] + add;
    if (i == 0) rowptr[0] = 0;
}

__global__ void cursor_kernel(const int* __restrict__ rowptr, int* __restrict__ cursor, int n)
{
    int i = blockIdx.x * blockDim.x + threadIdx.x;
    if (i < n) cursor[i] = rowptr[i];
}

// col entry: (src_row << 2) | edge_type
__global__ void scatter_kernel(const int* __restrict__ ti_src, const int* __restrict__ ti_dst,
                               const int* __restrict__ im_src, const int* __restrict__ im_dst,
                               const int* __restrict__ ub_src, const int* __restrict__ ub_dst,
                               const int* __restrict__ bu_src, const int* __restrict__ bu_dst,
                               int* __restrict__ cursor, int* __restrict__ col)
{
    int i = blockIdx.x * blockDim.x + threadIdx.x;
    if (i >= ETOT) return;
    int d, row, et;
    if (i < E_TI)                    { d = ti_dst[i];                 row = BASE_T + ti_src[i];                 et = 0; }
    else if (i < E_TI + E_IM)        { int e = i - E_TI;              row = BASE_G + im_src[e]; d = im_dst[e];  et = 1; }
    else if (i < E_TI + E_IM + E_UB) { int e = i - E_TI - E_IM;       row = BASE_U + ub_src[e]; d = ub_dst[e];  et = 2; }
    else                             { int e = i - E_TI - E_IM - E_UB; row = BASE_I + bu_src[e]; d = NI + bu_dst[e]; et = 3; }
    int p = atomicAdd(&cursor[d], 1);
    col[p] = (row << 2) | et;
}

// ----------------------- fused softmax-attention (gather) -----------------------

// F1: per dst wave: alpha per edge+head, per-head max, then ex=exp(a-max) into scratch.
__global__ __launch_bounds__(256) void f1_kernel(
    const int* __restrict__ rowptr, const int* __restrict__ rowend,
    const int* __restrict__ col,
    const float* __restrict__ kr, const float* __restrict__ q_i, const float* __restrict__ q_u,
    const float* __restrict__ prel,
    float* __restrict__ exbuf)
{
    int wid = (blockIdx.x << 2) + (threadIdx.x >> 6);
    if (wid >= ND) return;
    const int l = threadIdx.x & 63;
    const int h = l >> 3;

    const float* qrow = (wid < NI) ? q_i + (size_t)wid * HIDN
                                   : q_u + (size_t)(wid - NI) * HIDN;
    float2 qv = *(const float2*)(qrow + 2 * l);

    const int start = rowptr[wid], end = rowend[wid];
    float m = -3.0e38f;
    for (int p = start; p < end; ++p) {
        int pk = col[p];
        int row = pk >> 2, et = pk & 3;
        float2 kv = *(const float2*)(kr + (size_t)row * HIDN + 2 * l);
        float d2 = qv.x * kv.x + qv.y * kv.y;
        d2 += __shfl_xor(d2, 1);
        d2 += __shfl_xor(d2, 2);
        d2 += __shfl_xor(d2, 4);
        float alpha = d2 * prel[et * NHEAD + h] * 0.25f;
        m = fmaxf(m, alpha);
        if ((l & 7) == 0) exbuf[(size_t)p * NHEAD + h] = alpha;
    }
    for (int p = start; p < end; ++p) {
        float a = exbuf[(size_t)p * NHEAD + h];
        float ex = expf(a - m);
        if ((l & 7) == 0) exbuf[(size_t)p * NHEAD + h] = ex;
    }
}

// F2: per dst wave: agg = sum(ex * vr[src]) / (sum(ex)+1e-16), one coalesced write.
__global__ __launch_bounds__(256) void f2_kernel(
    const int* __restrict__ rowptr, const int* __restrict__ rowend,
    const int* __restrict__ col,
    const float* __restrict__ vr, const float* __restrict__ exbuf,
    float* __restrict__ agg_i, float* __restrict__ agg_u)
{
    int wid = (blockIdx.x << 2) + (threadIdx.x >> 6);
    if (wid >= ND) return;
    const int l = threadIdx.x & 63;
    const int h = l >> 3;

    const int start = rowptr[wid], end = rowend[wid];
    float ax = 0.f, ay = 0.f, den = 0.f;
    for (int p = start; p < end; ++p) {
        int pk = col[p];
        int row = pk >> 2;
        float ex = exbuf[(size_t)p * NHEAD + h];
        float2 vv = *(const float2*)(vr + (size_t)row * HIDN + 2 * l);
        ax = fmaf(ex, vv.x, ax);
        ay = fmaf(ex, vv.y, ay);
        den += ex;
    }
    float inv = 1.f / (den + 1e-16f);
    float* dst = (wid < NI) ? agg_i + (size_t)wid * HIDN
                            : agg_u + (size_t)(wid - NI) * HIDN;
    *(float2*)(dst + 2 * l) = make_float2(ax * inv, ay * inv);
}

extern "C" void kernel_launch(void* const* d_in, const int* in_sizes, int n_in,
                              void* d_out, int out_size, void* d_ws, size_t ws_size,
                              hipStream_t stream)
{
    const float* x_user = (const float*)d_in[0];
    const float* x_item = (const float*)d_in[1];
    const float* x_taste= (const float*)d_in[2];
    const float* x_image= (const float*)d_in[3];
    const float* Wk     = (const float*)d_in[4];
    const float* bk     = (const float*)d_in[5];
    const float* Wq     = (const float*)d_in[6];
    const float* bq     = (const float*)d_in[7];
    const float* Wv     = (const float*)d_in[8];
    const float* bv     = (const float*)d_in[9];
    const float* a_rel  = (const float*)d_in[10];
    const float* m_rel  = (const float*)d_in[11];
    const float* p_rel  = (const float*)d_in[12];
    const float* Wo     = (const float*)d_in[13];
    const float* bo     = (const float*)d_in[14];
    const float* skip   = (const float*)d_in[15];
    const int* ti_src = (const int*)d_in[16];
    const int* ti_dst = (const int*)d_in[17];
    const int* im_src = (const int*)d_in[18];
    const int* im_dst = (const int*)d_in[19];
    const int* ub_src = (const int*)d_in[20];
    const int* ub_dst = (const int*)d_in[21];
    const int* bu_src = (const int*)d_in[22];
    const int* bu_dst = (const int*)d_in[23];

    float* ws = (float*)d_ws;
    float* outp = (float*)d_out;
    (void)in_sizes; (void)n_in; (void)out_size;

    // ---- workspace layout (floats) — total ~54.05M fl = 216.2 MB ----
    size_t off = 0;
    auto alloc = [&](size_t n) { size_t o = off; off += n; return o; };
    const size_t o_cw   = alloc((size_t)2 * 4 * 129 * 128);   // reused as deg[] after pack
    const size_t o_pkh  = alloc((size_t)NMAT * MATSZ / 2);
    const size_t o_pkl  = alloc((size_t)NMAT * MATSZ / 2);
    const size_t o_bias = alloc((size_t)NMAT * HIDN);
    // combined kr table [u|i|t|g]; REUSED as [agg_i|agg_u] in F2 (kr dead after F1)
    const size_t o_kr   = alloc((size_t)(NU + NI + NT + NG) * HIDN);
    const size_t o_vr   = alloc((size_t)(NU + NI + NT + NG) * HIDN);
    const size_t o_q_i  = alloc((size_t)NI * HIDN);
    const size_t o_q_u  = alloc((size_t)NU * HIDN);
    const size_t o_int  = alloc((size_t)(ND + 1) + ND + 1024 + ETOT);

    if (ws_size < off * sizeof(float)) return;  // clean failure instead of OOB fault

    const size_t o_kr_u = o_kr;
    const size_t o_kr_i = o_kr_u + (size_t)NU * HIDN;
    const size_t o_kr_t = o_kr_i + (size_t)NI * HIDN;
    const size_t o_kr_g = o_kr_t + (size_t)NT * HIDN;
    const size_t o_vr_u = o_vr;
    const size_t o_vr_i = o_vr_u + (size_t)NU * HIDN;
    const size_t o_vr_t = o_vr_i + (size_t)NI * HIDN;
    const size_t o_vr_g = o_vr_t + (size_t)NT * HIDN;

    short* pkh  = (short*)(ws + o_pkh);
    short* pkl  = (short*)(ws + o_pkl);
    float* bias = ws + o_bias;

    int* deg    = (int*)(ws + o_cw);        // overlays cw (dead after pack)
    int* rowptr = (int*)(ws + o_int);
    int* cursor = rowptr + (ND + 1);
    int* tops   = cursor + ND;
    int* col    = tops + 1024;

    float* exbuf = outp;                    // ETOT*8 = 8.8M <= 8.96M, dead until epilogue

    // agg overlays kr region (kr dead after F1)
    float* agg_i = ws + o_kr;
    float* agg_u = ws + o_kr + (size_t)NI * HIDN;

    // ---- 1. combined weights + MFMA pack ----
    {
        int total = 2 * 4 * 129 * 128;
        build_cw_kernel<<<(total + 255) / 256, 256, 0, stream>>>(
            Wk, bk, Wv, bv, a_rel, m_rel, ws + o_cw);
        int ptotal = NMAT * MATSZ + NMAT * HIDN;
        pack_kernel<<<(ptotal + 255) / 256, 256, 0, stream>>>(
            ws + o_cw, Wq, bq, Wo, bo, pkh, pkl, bias);
    }

    // ---- 2. split-bf16 MFMA projections ----
    mfma_proj_kernel<3><<<(NU + 63) / 64, 256, 0, stream>>>(
        x_user, NU, pkh, pkl, bias, 0, 4, 8,
        ws + o_kr_u, ws + o_vr_u, ws + o_q_u);
    mfma_proj_kernel<3><<<(NI + 63) / 64, 256, 0, stream>>>(
        x_item, NI, pkh, pkl, bias, 1, 5, 9,
        ws + o_kr_i, ws + o_vr_i, ws + o_q_i);
    mfma_proj_kernel<2><<<(NT + 63) / 64, 256, 0, stream>>>(
        x_taste, NT, pkh, pkl, bias, 2, 6, 0,
        ws + o_kr_t, ws + o_vr_t, nullptr);
    mfma_proj_kernel<2><<<(NG + 63) / 64, 256, 0, stream>>>(
        x_image, NG, pkh, pkl, bias, 3, 7, 0,
        ws + o_kr_g, ws + o_vr_g, nullptr);

    // ---- 3. CSR build (after pack: deg overlays cw) ----
    hipMemsetAsync(deg, 0, ND * sizeof(int), stream);
    hist_kernel<<<(ETOT + 255) / 256, 256, 0, stream>>>(ti_dst, im_dst, ub_dst, bu_dst, deg);
    const int NB1 = (ND + 255) / 256;
    scan1_kernel<<<NB1, 256, 0, stream>>>(deg, tops, ND);
    scan2_kernel<<<1, 1024, 0, stream>>>(tops, NB1);
    scan3_kernel<<<NB1, 256, 0, stream>>>(deg, tops, rowptr, ND);
    cursor_kernel<<<(ND + 255) / 256, 256, 0, stream>>>(rowptr, cursor, ND);
    scatter_kernel<<<(ETOT + 255) / 256, 256, 0, stream>>>(
        ti_src, ti_dst, im_src, im_dst, ub_src, ub_dst, bu_src, bu_dst, cursor, col);
    // after scatter, cursor[d] == row end

    // ---- 4. F1: alpha + max + exp ----
    const int NBW = (ND + 3) / 4;
    f1_kernel<<<NBW, 256, 0, stream>>>(
        rowptr, cursor, col, ws + o_kr, ws + o_q_i, ws + o_q_u, p_rel, exbuf);

    // ---- 5. F2: weighted gather + normalize (writes agg over kr region) ----
    f2_kernel<<<NBW, 256, 0, stream>>>(
        rowptr, cursor, col, ws + o_vr, exbuf, agg_i, agg_u);

    // ---- 6. epilogue GEMMs ----
    mfma_out_kernel<<<(NI + 63) / 64, 256, 0, stream>>>(
        agg_i, NI, pkh, pkl, bias, 10, x_item, skip + 0, outp);
    mfma_out_kernel<<<(NU + 63) / 64, 256, 0, stream>>>(
        agg_u, NU, pkh, pkl, bias, 11, x_user, skip + 1,
        outp + (size_t)NI * HIDN);
}

// Round 5
// 604.366 us; speedup vs baseline: 2.2175x; 1.3317x over previous
//
#include <hip/hip_runtime.h>
#include <math.h>

// ---------------------------------------------------------------------------
// MultiModalFusionGAT — round 5
//   Projections/epilogue: split-bf16 MFMA. kr/vr tables now stored bf16
//   (halves edge-gather traffic; q stays fp32).
//   Edge phase: single fused kernel (alpha+max+exp+weighted-gather+normalize),
//   one wave per dst, 2x unrolled gathers. CSR build unchanged.
// ---------------------------------------------------------------------------

namespace {
constexpr int HIDN  = 128;
constexpr int NHEAD = 8;

constexpr int NU = 20000, NI = 50000, NT = 50000, NG = 50000;
constexpr int E_TI = 50000, E_IM = 50000, E_UB = 500000, E_BU = 500000;
constexpr int ETOT = E_TI + E_IM + E_UB + E_BU;   // 1,100,000
constexpr int ND   = NI + NU;                     // dst nodes: items then users

constexpr int BASE_U = 0;
constexpr int BASE_I = NU;
constexpr int BASE_T = NU + NI;
constexpr int BASE_G = NU + NI + NT;

constexpr int NMAT = 12;           // 0..3 k, 4..7 v, 8/9 q(user,item), 10/11 Wo(item,user)
constexpr int MATSZ = 128 * 128;
constexpr int XP = 132;
}

typedef __attribute__((ext_vector_type(8))) short short8v;
typedef __attribute__((ext_vector_type(4))) float f32x4;

__device__ __forceinline__ unsigned short bf16rne(float f) {
    unsigned u = __float_as_uint(f);
    unsigned r = (u + 0x7fffu + ((u >> 16) & 1u)) >> 16;
    return (unsigned short)r;
}
__device__ __forceinline__ float bf16f(unsigned short h) {
    return __uint_as_float(((unsigned)h) << 16);
}

// cw layout: [which(2)][type(4)][row(129)][col(128)]; row 128 = transformed bias
__global__ void build_cw_kernel(const float* __restrict__ Wk, const float* __restrict__ bk,
                                const float* __restrict__ Wv, const float* __restrict__ bv,
                                const float* __restrict__ a_rel, const float* __restrict__ m_rel,
                                float* __restrict__ cw)
{
    const int total = 2 * 4 * 129 * 128;
    int idx = blockIdx.x * blockDim.x + threadIdx.x;
    if (idx >= total) return;
    int c     = idx & 127;
    int r     = (idx >> 7) % 129;
    int t     = ((idx >> 7) / 129) & 3;
    int which = idx / (4 * 129 * 128);
    const int et_map[4] = {2, 3, 0, 1};
    int et = et_map[t];
    const float* W = (which == 0 ? Wk : Wv) + (size_t)t * HIDN * HIDN;
    const float* b = (which == 0 ? bk : bv) + (size_t)t * HIDN;
    const float* A = (which == 0 ? a_rel : m_rel) + (size_t)et * NHEAD * 16 * 16;
    int h = c >> 4, e2 = c & 15;
    float s = 0.f;
#pragma unroll
    for (int d = 0; d < 16; ++d) {
        float w = (r == 128) ? b[h * 16 + d] : W[(size_t)r * HIDN + h * 16 + d];
        s = fmaf(w, A[h * 256 + d * 16 + e2], s);
    }
    cw[idx] = s;
}

__global__ void pack_kernel(const float* __restrict__ cw,
                            const float* __restrict__ Wq, const float* __restrict__ bq,
                            const float* __restrict__ Wo, const float* __restrict__ bo,
                            short* __restrict__ pkh, short* __restrict__ pkl,
                            float* __restrict__ bias)
{
    const int total = NMAT * MATSZ + NMAT * HIDN;
    int idx = blockIdx.x * blockDim.x + threadIdx.x;
    if (idx >= total) return;
    if (idx < NMAT * MATSZ) {
        int mat = idx >> 14;
        int rem = idx & (MATSZ - 1);
        int i    = rem & 7;
        int lane = (rem >> 3) & 63;
        int ct   = (rem >> 9) & 7;
        int ks   = rem >> 12;
        int k   = ks * 32 + ((lane >> 4) & 3) * 8 + i;
        int col = ct * 16 + (lane & 15);
        float v;
        if (mat < 8)       v = cw[(size_t)mat * 129 * 128 + (size_t)k * 128 + col];
        else if (mat < 10) v = Wq[(size_t)(mat - 8) * MATSZ + (size_t)k * 128 + col];
        else               v = Wo[(size_t)(mat - 10) * MATSZ + (size_t)k * 128 + col];
        unsigned short hb = bf16rne(v);
        float rest = v - bf16f(hb);
        pkh[idx] = (short)hb;
        pkl[idx] = (short)bf16rne(rest);
    } else {
        int b = idx - NMAT * MATSZ;
        int mat = b >> 7, col = b & 127;
        float v;
        if (mat < 8)       v = cw[(size_t)mat * 129 * 128 + (size_t)128 * 128 + col];
        else if (mat < 10) v = bq[(mat - 8) * HIDN + col];
        else               v = bo[(mat - 10) * HIDN + col];
        bias[b] = v;
    }
}

// Split-bf16 MFMA GEMM; d0/d1 (k,v) written as bf16 tables, d2 (q) fp32.
template<int NM>
__global__ __launch_bounds__(256) void mfma_proj_kernel(
    const float* __restrict__ x, int M,
    const short* __restrict__ pkh, const short* __restrict__ pkl,
    const float* __restrict__ bias,
    int m0, int m1, int m2,
    unsigned short* __restrict__ d0, unsigned short* __restrict__ d1,
    float* __restrict__ d2)
{
    __shared__ float xs[64 * XP];
    const int t  = threadIdx.x;
    const int r0 = blockIdx.x * 64;
    const int rows = min(64, M - r0);

#pragma unroll
    for (int p = 0; p < 8; ++p) {
        int f = p * 256 + t;
        int row = f >> 5, c4 = f & 31;
        float4 v = make_float4(0.f, 0.f, 0.f, 0.f);
        if (row < rows) v = *(const float4*)(x + (size_t)(r0 + row) * HIDN + c4 * 4);
        *(float4*)&xs[row * XP + c4 * 4] = v;
    }
    __syncthreads();

    const int l = t & 63, w = t >> 6;
    const int arow = w * 16 + (l & 15);
    const int kgrp = l >> 4;

    short8v ahi[4], alo[4];
#pragma unroll
    for (int ks = 0; ks < 4; ++ks) {
        const float* xp = &xs[arow * XP + ks * 32 + kgrp * 8];
        float4 va = *(const float4*)xp;
        float4 vb = *(const float4*)(xp + 4);
        float vv[8] = {va.x, va.y, va.z, va.w, vb.x, vb.y, vb.z, vb.w};
#pragma unroll
        for (int i = 0; i < 8; ++i) {
            unsigned short hb = bf16rne(vv[i]);
            ahi[ks][i] = (short)hb;
            alo[ks][i] = (short)bf16rne(vv[i] - bf16f(hb));
        }
    }

    for (int mi = 0; mi < NM; ++mi) {
        const int mat = (mi == 0) ? m0 : (mi == 1) ? m1 : m2;
        const short8v* bh = (const short8v*)(pkh + (size_t)mat * MATSZ);
        const short8v* bl = (const short8v*)(pkl + (size_t)mat * MATSZ);
        const float*   bs = bias + mat * HIDN;

        f32x4 acc[8];
        f32x4 z; z[0] = 0.f; z[1] = 0.f; z[2] = 0.f; z[3] = 0.f;
#pragma unroll
        for (int ct = 0; ct < 8; ++ct) acc[ct] = z;

#pragma unroll
        for (int ct = 0; ct < 8; ++ct) {
#pragma unroll
            for (int ks = 0; ks < 4; ++ks) {
                short8v b1 = bh[(ks * 8 + ct) * 64 + l];
                short8v b2 = bl[(ks * 8 + ct) * 64 + l];
                acc[ct] = __builtin_amdgcn_mfma_f32_16x16x32_bf16(ahi[ks], b1, acc[ct], 0, 0, 0);
                acc[ct] = __builtin_amdgcn_mfma_f32_16x16x32_bf16(alo[ks], b1, acc[ct], 0, 0, 0);
                acc[ct] = __builtin_amdgcn_mfma_f32_16x16x32_bf16(ahi[ks], b2, acc[ct], 0, 0, 0);
            }
        }

        const int crow0 = w * 16 + kgrp * 4;
        const int ccol  = l & 15;
        if (mi < 2) {
            unsigned short* dst = (mi == 0) ? d0 : d1;
#pragma unroll
            for (int ct = 0; ct < 8; ++ct) {
                float bv = bs[ct * 16 + ccol];
#pragma unroll
                for (int j = 0; j < 4; ++j) {
                    int grow = r0 + crow0 + j;
                    if (grow < M)
                        dst[(size_t)grow * HIDN + ct * 16 + ccol] = bf16rne(acc[ct][j] + bv);
                }
            }
        } else {
#pragma unroll
            for (int ct = 0; ct < 8; ++ct) {
                float bv = bs[ct * 16 + ccol];
#pragma unroll
                for (int j = 0; j < 4; ++j) {
                    int grow = r0 + crow0 + j;
                    if (grow < M)
                        d2[(size_t)grow * HIDN + ct * 16 + ccol] = acc[ct][j] + bv;
                }
            }
        }
    }
}

// Epilogue: out = gate*(gelu(agg) @ Wo + bo) + (1-gate)*xin
__global__ __launch_bounds__(256) void mfma_out_kernel(
    const float* __restrict__ agg, int M,
    const short* __restrict__ pkh, const short* __restrict__ pkl,
    const float* __restrict__ bias, int mat,
    const float* __restrict__ xin, const float* __restrict__ skip_ptr,
    float* __restrict__ out)
{
    __shared__ float xs[64 * XP];
    const int t  = threadIdx.x;
    const int r0 = blockIdx.x * 64;
    const int rows = min(64, M - r0);

#pragma unroll
    for (int p = 0; p < 8; ++p) {
        int f = p * 256 + t;
        int row = f >> 5, c4 = f & 31;
        float4 v = make_float4(0.f, 0.f, 0.f, 0.f);
        if (row < rows) v = *(const float4*)(agg + (size_t)(r0 + row) * HIDN + c4 * 4);
        *(float4*)&xs[row * XP + c4 * 4] = v;
    }
    __syncthreads();

    const int l = t & 63, w = t >> 6;
    const int arow = w * 16 + (l & 15);
    const int kgrp = l >> 4;

    short8v ahi[4], alo[4];
#pragma unroll
    for (int ks = 0; ks < 4; ++ks) {
        const float* xp = &xs[arow * XP + ks * 32 + kgrp * 8];
        float4 va = *(const float4*)xp;
        float4 vb = *(const float4*)(xp + 4);
        float vv[8] = {va.x, va.y, va.z, va.w, vb.x, vb.y, vb.z, vb.w};
#pragma unroll
        for (int i = 0; i < 8; ++i) {
            float g = 0.5f * vv[i] * (1.0f + erff(vv[i] * 0.70710678118654752440f));
            unsigned short hb = bf16rne(g);
            ahi[ks][i] = (short)hb;
            alo[ks][i] = (short)bf16rne(g - bf16f(hb));
        }
    }

    const short8v* bh = (const short8v*)(pkh + (size_t)mat * MATSZ);
    const short8v* bl = (const short8v*)(pkl + (size_t)mat * MATSZ);
    const float*   bs = bias + mat * HIDN;

    f32x4 acc[8];
    f32x4 z; z[0] = 0.f; z[1] = 0.f; z[2] = 0.f; z[3] = 0.f;
#pragma unroll
    for (int ct = 0; ct < 8; ++ct) acc[ct] = z;

#pragma unroll
    for (int ct = 0; ct < 8; ++ct) {
#pragma unroll
        for (int ks = 0; ks < 4; ++ks) {
            short8v b1 = bh[(ks * 8 + ct) * 64 + l];
            short8v b2 = bl[(ks * 8 + ct) * 64 + l];
            acc[ct] = __builtin_amdgcn_mfma_f32_16x16x32_bf16(ahi[ks], b1, acc[ct], 0, 0, 0);
            acc[ct] = __builtin_amdgcn_mfma_f32_16x16x32_bf16(alo[ks], b1, acc[ct], 0, 0, 0);
            acc[ct] = __builtin_amdgcn_mfma_f32_16x16x32_bf16(ahi[ks], b2, acc[ct], 0, 0, 0);
        }
    }

    const float gate = 1.f / (1.f + expf(-skip_ptr[0]));
    const int crow0 = w * 16 + kgrp * 4;
    const int ccol  = l & 15;
#pragma unroll
    for (int ct = 0; ct < 8; ++ct) {
        float bv = bs[ct * 16 + ccol];
#pragma unroll
        for (int j = 0; j < 4; ++j) {
            int grow = r0 + crow0 + j;
            if (grow < M) {
                size_t o = (size_t)grow * HIDN + ct * 16 + ccol;
                out[o] = gate * (acc[ct][j] + bv) + (1.f - gate) * xin[o];
            }
        }
    }
}

// ----------------------- CSR construction -----------------------

__global__ void hist_kernel(const int* __restrict__ ti_dst, const int* __restrict__ im_dst,
                            const int* __restrict__ ub_dst, const int* __restrict__ bu_dst,
                            int* __restrict__ deg)
{
    int i = blockIdx.x * blockDim.x + threadIdx.x;
    if (i >= ETOT) return;
    int d;
    if (i < E_TI)                     d = ti_dst[i];
    else if (i < E_TI + E_IM)         d = im_dst[i - E_TI];
    else if (i < E_TI + E_IM + E_UB)  d = ub_dst[i - E_TI - E_IM];
    else                              d = NI + bu_dst[i - E_TI - E_IM - E_UB];
    atomicAdd(&deg[d], 1);
}

__global__ void scan1_kernel(int* __restrict__ deg, int* __restrict__ tops, int n)
{
    __shared__ int sh[256];
    int i = blockIdx.x * 256 + threadIdx.x;
    int v = (i < n) ? deg[i] : 0;
    sh[threadIdx.x] = v;
    __syncthreads();
    for (int o = 1; o < 256; o <<= 1) {
        int t = (threadIdx.x >= o) ? sh[threadIdx.x - o] : 0;
        __syncthreads();
        sh[threadIdx.x] += t;
        __syncthreads();
    }
    if (i < n) deg[i] = sh[threadIdx.x];
    if (threadIdx.x == 255) tops[blockIdx.x] = sh[255];
}

__global__ void scan2_kernel(int* __restrict__ tops, int nb)
{
    __shared__ int sh[1024];
    int v = (threadIdx.x < nb) ? tops[threadIdx.x] : 0;
    sh[threadIdx.x] = v;
    __syncthreads();
    for (int o = 1; o < 1024; o <<= 1) {
        int t = (threadIdx.x >= o) ? sh[threadIdx.x - o] : 0;
        __syncthreads();
        sh[threadIdx.x] += t;
        __syncthreads();
    }
    if (threadIdx.x < nb) tops[threadIdx.x] = sh[threadIdx.x];
}

__global__ void scan3_kernel(const int* __restrict__ part, const int* __restrict__ tops,
                             int* __restrict__ rowptr, int n)
{
    int i = blockIdx.x * 256 + threadIdx.x;
    if (i >= n) return;
    int add = (blockIdx.x > 0) ? tops[blockIdx.x - 1] : 0;
    rowptr[i + 1] = part[i] + add;
    if (i == 0) rowptr[0] = 0;
}

__global__ void cursor_kernel(const int* __restrict__ rowptr, int* __restrict__ cursor, int n)
{
    int i = blockIdx.x * blockDim.x + threadIdx.x;
    if (i < n) cursor[i] = rowptr[i];
}

// col entry: (src_row << 2) | edge_type
__global__ void scatter_kernel(const int* __restrict__ ti_src, const int* __restrict__ ti_dst,
                               const int* __restrict__ im_src, const int* __restrict__ im_dst,
                               const int* __restrict__ ub_src, const int* __restrict__ ub_dst,
                               const int* __restrict__ bu_src, const int* __restrict__ bu_dst,
                               int* __restrict__ cursor, int* __restrict__ col)
{
    int i = blockIdx.x * blockDim.x + threadIdx.x;
    if (i >= ETOT) return;
    int d, row, et;
    if (i < E_TI)                    { d = ti_dst[i];                 row = BASE_T + ti_src[i];                 et = 0; }
    else if (i < E_TI + E_IM)        { int e = i - E_TI;              row = BASE_G + im_src[e]; d = im_dst[e];  et = 1; }
    else if (i < E_TI + E_IM + E_UB) { int e = i - E_TI - E_IM;       row = BASE_U + ub_src[e]; d = ub_dst[e];  et = 2; }
    else                             { int e = i - E_TI - E_IM - E_UB; row = BASE_I + bu_src[e]; d = NI + bu_dst[e]; et = 3; }
    int p = atomicAdd(&cursor[d], 1);
    col[p] = (row << 2) | et;
}

// ------------------- fused edge softmax-attention (bf16 gather) -------------------
// One wave per dst. Pass 1: alpha (q fp32 · kr bf16), per-head max, alpha -> exbuf.
// Pass 2: ex = exp(alpha-max), weighted vr gather, den; one coalesced agg write.
__global__ __launch_bounds__(256) void f12_kernel(
    const int* __restrict__ rowptr, const int* __restrict__ rowend,
    const int* __restrict__ col,
    const unsigned int* __restrict__ krw,   // bf16x2 per uint, row stride 64
    const float* __restrict__ q_i, const float* __restrict__ q_u,
    const unsigned int* __restrict__ vrw,
    const float* __restrict__ prel,
    float* __restrict__ exbuf,
    float* __restrict__ agg_i, float* __restrict__ agg_u)
{
    int wid = (blockIdx.x << 2) + (threadIdx.x >> 6);
    if (wid >= ND) return;
    const int l = threadIdx.x & 63;
    const int h = l >> 3;

    const float* qrow = (wid < NI) ? q_i + (size_t)wid * HIDN
                                   : q_u + (size_t)(wid - NI) * HIDN;
    float2 qv = *(const float2*)(qrow + 2 * l);

    const int start = rowptr[wid], end = rowend[wid];
    float m = -3.0e38f;

    // ---- pass 1: alpha + max ----
    int p = start;
    for (; p + 1 < end; p += 2) {
        int pk0 = col[p], pk1 = col[p + 1];
        unsigned int u0 = krw[(size_t)(pk0 >> 2) * 64 + l];
        unsigned int u1 = krw[(size_t)(pk1 >> 2) * 64 + l];
        float d0 = qv.x * __uint_as_float(u0 << 16) + qv.y * __uint_as_float(u0 & 0xffff0000u);
        float d1 = qv.x * __uint_as_float(u1 << 16) + qv.y * __uint_as_float(u1 & 0xffff0000u);
        d0 += __shfl_xor(d0, 1); d1 += __shfl_xor(d1, 1);
        d0 += __shfl_xor(d0, 2); d1 += __shfl_xor(d1, 2);
        d0 += __shfl_xor(d0, 4); d1 += __shfl_xor(d1, 4);
        float a0 = d0 * prel[(pk0 & 3) * NHEAD + h] * 0.25f;
        float a1 = d1 * prel[(pk1 & 3) * NHEAD + h] * 0.25f;
        m = fmaxf(m, fmaxf(a0, a1));
        if ((l & 7) == 0) {
            exbuf[(size_t)p * NHEAD + h] = a0;
            exbuf[(size_t)(p + 1) * NHEAD + h] = a1;
        }
    }
    if (p < end) {
        int pk0 = col[p];
        unsigned int u0 = krw[(size_t)(pk0 >> 2) * 64 + l];
        float d0 = qv.x * __uint_as_float(u0 << 16) + qv.y * __uint_as_float(u0 & 0xffff0000u);
        d0 += __shfl_xor(d0, 1);
        d0 += __shfl_xor(d0, 2);
        d0 += __shfl_xor(d0, 4);
        float a0 = d0 * prel[(pk0 & 3) * NHEAD + h] * 0.25f;
        m = fmaxf(m, a0);
        if ((l & 7) == 0) exbuf[(size_t)p * NHEAD + h] = a0;
    }

    // ---- pass 2: exp + weighted gather + normalize ----
    float ax = 0.f, ay = 0.f, den = 0.f;
    p = start;
    for (; p + 1 < end; p += 2) {
        int pk0 = col[p], pk1 = col[p + 1];
        float e0 = expf(exbuf[(size_t)p * NHEAD + h] - m);
        float e1 = expf(exbuf[(size_t)(p + 1) * NHEAD + h] - m);
        unsigned int u0 = vrw[(size_t)(pk0 >> 2) * 64 + l];
        unsigned int u1 = vrw[(size_t)(pk1 >> 2) * 64 + l];
        ax = fmaf(e0, __uint_as_float(u0 << 16), ax);
        ay = fmaf(e0, __uint_as_float(u0 & 0xffff0000u), ay);
        ax = fmaf(e1, __uint_as_float(u1 << 16), ax);
        ay = fmaf(e1, __uint_as_float(u1 & 0xffff0000u), ay);
        den += e0 + e1;
    }
    if (p < end) {
        int pk0 = col[p];
        float e0 = expf(exbuf[(size_t)p * NHEAD + h] - m);
        unsigned int u0 = vrw[(size_t)(pk0 >> 2) * 64 + l];
        ax = fmaf(e0, __uint_as_float(u0 << 16), ax);
        ay = fmaf(e0, __uint_as_float(u0 & 0xffff0000u), ay);
        den += e0;
    }

    float inv = 1.f / (den + 1e-16f);
    float* dst = (wid < NI) ? agg_i + (size_t)wid * HIDN
                            : agg_u + (size_t)(wid - NI) * HIDN;
    *(float2*)(dst + 2 * l) = make_float2(ax * inv, ay * inv);
}

extern "C" void kernel_launch(void* const* d_in, const int* in_sizes, int n_in,
                              void* d_out, int out_size, void* d_ws, size_t ws_size,
                              hipStream_t stream)
{
    const float* x_user = (const float*)d_in[0];
    const float* x_item = (const float*)d_in[1];
    const float* x_taste= (const float*)d_in[2];
    const float* x_image= (const float*)d_in[3];
    const float* Wk     = (const float*)d_in[4];
    const float* bk     = (const float*)d_in[5];
    const float* Wq     = (const float*)d_in[6];
    const float* bq     = (const float*)d_in[7];
    const float* Wv     = (const float*)d_in[8];
    const float* bv     = (const float*)d_in[9];
    const float* a_rel  = (const float*)d_in[10];
    const float* m_rel  = (const float*)d_in[11];
    const float* p_rel  = (const float*)d_in[12];
    const float* Wo     = (const float*)d_in[13];
    const float* bo     = (const float*)d_in[14];
    const float* skip   = (const float*)d_in[15];
    const int* ti_src = (const int*)d_in[16];
    const int* ti_dst = (const int*)d_in[17];
    const int* im_src = (const int*)d_in[18];
    const int* im_dst = (const int*)d_in[19];
    const int* ub_src = (const int*)d_in[20];
    const int* ub_dst = (const int*)d_in[21];
    const int* bu_src = (const int*)d_in[22];
    const int* bu_dst = (const int*)d_in[23];

    float* ws = (float*)d_ws;
    float* outp = (float*)d_out;
    (void)in_sizes; (void)n_in; (void)out_size;

    // ---- workspace layout (floats) — total ~41.3M fl = 165 MB ----
    size_t off = 0;
    auto alloc = [&](size_t n) { size_t o = off; off += n; return o; };
    const size_t o_cw   = alloc((size_t)2 * 4 * 129 * 128);   // reused as deg[] after pack
    const size_t o_pkh  = alloc((size_t)NMAT * MATSZ / 2);
    const size_t o_pkl  = alloc((size_t)NMAT * MATSZ / 2);
    const size_t o_bias = alloc((size_t)NMAT * HIDN);
    const size_t o_krb  = alloc((size_t)(NU + NI + NT + NG) * HIDN / 2);  // bf16 table
    const size_t o_vrb  = alloc((size_t)(NU + NI + NT + NG) * HIDN / 2);  // bf16 table
    const size_t o_q_i  = alloc((size_t)NI * HIDN);
    const size_t o_q_u  = alloc((size_t)NU * HIDN);
    const size_t o_agg  = alloc((size_t)(NI + NU) * HIDN);
    const size_t o_int  = alloc((size_t)(ND + 1) + ND + 1024 + ETOT);

    if (ws_size < off * sizeof(float)) return;  // clean failure instead of OOB fault

    unsigned short* krb = (unsigned short*)(ws + o_krb);
    unsigned short* vrb = (unsigned short*)(ws + o_vrb);
    unsigned short* krb_u = krb;
    unsigned short* krb_i = krb_u + (size_t)NU * HIDN;
    unsigned short* krb_t = krb_i + (size_t)NI * HIDN;
    unsigned short* krb_g = krb_t + (size_t)NT * HIDN;
    unsigned short* vrb_u = vrb;
    unsigned short* vrb_i = vrb_u + (size_t)NU * HIDN;
    unsigned short* vrb_t = vrb_i + (size_t)NI * HIDN;
    unsigned short* vrb_g = vrb_t + (size_t)NT * HIDN;

    short* pkh  = (short*)(ws + o_pkh);
    short* pkl  = (short*)(ws + o_pkl);
    float* bias = ws + o_bias;

    int* deg    = (int*)(ws + o_cw);        // overlays cw (dead after pack)
    int* rowptr = (int*)(ws + o_int);
    int* cursor = rowptr + (ND + 1);
    int* tops   = cursor + ND;
    int* col    = tops + 1024;

    float* exbuf = outp;                    // ETOT*8 = 8.8M <= 8.96M, dead until epilogue
    float* agg_i = ws + o_agg;
    float* agg_u = ws + o_agg + (size_t)NI * HIDN;

    // ---- 1. combined weights + MFMA pack ----
    {
        int total = 2 * 4 * 129 * 128;
        build_cw_kernel<<<(total + 255) / 256, 256, 0, stream>>>(
            Wk, bk, Wv, bv, a_rel, m_rel, ws + o_cw);
        int ptotal = NMAT * MATSZ + NMAT * HIDN;
        pack_kernel<<<(ptotal + 255) / 256, 256, 0, stream>>>(
            ws + o_cw, Wq, bq, Wo, bo, pkh, pkl, bias);
    }

    // ---- 2. split-bf16 MFMA projections (kr/vr -> bf16 tables, q -> fp32) ----
    mfma_proj_kernel<3><<<(NU + 63) / 64, 256, 0, stream>>>(
        x_user, NU, pkh, pkl, bias, 0, 4, 8, krb_u, vrb_u, ws + o_q_u);
    mfma_proj_kernel<3><<<(NI + 63) / 64, 256, 0, stream>>>(
        x_item, NI, pkh, pkl, bias, 1, 5, 9, krb_i, vrb_i, ws + o_q_i);
    mfma_proj_kernel<2><<<(NT + 63) / 64, 256, 0, stream>>>(
        x_taste, NT, pkh, pkl, bias, 2, 6, 0, krb_t, vrb_t, nullptr);
    mfma_proj_kernel<2><<<(NG + 63) / 64, 256, 0, stream>>>(
        x_image, NG, pkh, pkl, bias, 3, 7, 0, krb_g, vrb_g, nullptr);

    // ---- 3. CSR build ----
    hipMemsetAsync(deg, 0, ND * sizeof(int), stream);
    hist_kernel<<<(ETOT + 255) / 256, 256, 0, stream>>>(ti_dst, im_dst, ub_dst, bu_dst, deg);
    const int NB1 = (ND + 255) / 256;
    scan1_kernel<<<NB1, 256, 0, stream>>>(deg, tops, ND);
    scan2_kernel<<<1, 1024, 0, stream>>>(tops, NB1);
    scan3_kernel<<<NB1, 256, 0, stream>>>(deg, tops, rowptr, ND);
    cursor_kernel<<<(ND + 255) / 256, 256, 0, stream>>>(rowptr, cursor, ND);
    scatter_kernel<<<(ETOT + 255) / 256, 256, 0, stream>>>(
        ti_src, ti_dst, im_src, im_dst, ub_src, ub_dst, bu_src, bu_dst, cursor, col);
    // after scatter, cursor[d] == row end

    // ---- 4. fused edge softmax-attention ----
    const int NBW = (ND + 3) / 4;
    f12_kernel<<<NBW, 256, 0, stream>>>(
        rowptr, cursor, col,
        (const unsigned int*)krb, ws + o_q_i, ws + o_q_u,
        (const unsigned int*)vrb, p_rel,
        exbuf, agg_i, agg_u);

    // ---- 5. epilogue GEMMs ----
    mfma_out_kernel<<<(NI + 63) / 64, 256, 0, stream>>>(
        agg_i, NI, pkh, pkl, bias, 10, x_item, skip + 0, outp);
    mfma_out_kernel<<<(NU + 63) / 64, 256, 0, stream>>>(
        agg_u, NU, pkh, pkl, bias, 11, x_user, skip + 1,
        outp + (size_t)NI * HIDN);
}

// Round 6
// 422.859 us; speedup vs baseline: 3.1694x; 1.4292x over previous
//
#include <hip/hip_runtime.h>
#include <math.h>

// ---------------------------------------------------------------------------
// MultiModalFusionGAT — round 6
//   Projections/epilogue: split-bf16 MFMA, all four node types merged into
//   ONE launch; both epilogues merged into one launch.
//   Edge phase: ONE-pass online-softmax gather kernel (no exbuf, no stores
//   in the loop, 4 independent gathers in flight per 2-edge iteration).
// ---------------------------------------------------------------------------

namespace {
constexpr int HIDN  = 128;
constexpr int NHEAD = 8;

constexpr int NU = 20000, NI = 50000, NT = 50000, NG = 50000;
constexpr int E_TI = 50000, E_IM = 50000, E_UB = 500000, E_BU = 500000;
constexpr int ETOT = E_TI + E_IM + E_UB + E_BU;   // 1,100,000
constexpr int ND   = NI + NU;                     // dst nodes: items then users

constexpr int BASE_U = 0;
constexpr int BASE_I = NU;
constexpr int BASE_T = NU + NI;
constexpr int BASE_G = NU + NI + NT;

constexpr int NMAT = 12;           // 0..3 k, 4..7 v, 8/9 q(user,item), 10/11 Wo(item,user)
constexpr int MATSZ = 128 * 128;
constexpr int XP = 132;

constexpr int NBU = (NU + 63) / 64;   // 313
constexpr int NBI = (NI + 63) / 64;   // 782
constexpr int NBT = (NT + 63) / 64;   // 782
constexpr int NBG = (NG + 63) / 64;   // 782
}

typedef __attribute__((ext_vector_type(8))) short short8v;
typedef __attribute__((ext_vector_type(4))) float f32x4;

__device__ __forceinline__ unsigned short bf16rne(float f) {
    unsigned u = __float_as_uint(f);
    unsigned r = (u + 0x7fffu + ((u >> 16) & 1u)) >> 16;
    return (unsigned short)r;
}
__device__ __forceinline__ float bf16f(unsigned short h) {
    return __uint_as_float(((unsigned)h) << 16);
}
__device__ __forceinline__ float bflo(unsigned int u) { return __uint_as_float(u << 16); }
__device__ __forceinline__ float bfhi(unsigned int u) { return __uint_as_float(u & 0xffff0000u); }

// cw layout: [which(2)][type(4)][row(129)][col(128)]; row 128 = transformed bias
__global__ void build_cw_kernel(const float* __restrict__ Wk, const float* __restrict__ bk,
                                const float* __restrict__ Wv, const float* __restrict__ bv,
                                const float* __restrict__ a_rel, const float* __restrict__ m_rel,
                                float* __restrict__ cw)
{
    const int total = 2 * 4 * 129 * 128;
    int idx = blockIdx.x * blockDim.x + threadIdx.x;
    if (idx >= total) return;
    int c     = idx & 127;
    int r     = (idx >> 7) % 129;
    int t     = ((idx >> 7) / 129) & 3;
    int which = idx / (4 * 129 * 128);
    const int et_map[4] = {2, 3, 0, 1};
    int et = et_map[t];
    const float* W = (which == 0 ? Wk : Wv) + (size_t)t * HIDN * HIDN;
    const float* b = (which == 0 ? bk : bv) + (size_t)t * HIDN;
    const float* A = (which == 0 ? a_rel : m_rel) + (size_t)et * NHEAD * 16 * 16;
    int h = c >> 4, e2 = c & 15;
    float s = 0.f;
#pragma unroll
    for (int d = 0; d < 16; ++d) {
        float w = (r == 128) ? b[h * 16 + d] : W[(size_t)r * HIDN + h * 16 + d];
        s = fmaf(w, A[h * 256 + d * 16 + e2], s);
    }
    cw[idx] = s;
}

__global__ void pack_kernel(const float* __restrict__ cw,
                            const float* __restrict__ Wq, const float* __restrict__ bq,
                            const float* __restrict__ Wo, const float* __restrict__ bo,
                            short* __restrict__ pkh, short* __restrict__ pkl,
                            float* __restrict__ bias)
{
    const int total = NMAT * MATSZ + NMAT * HIDN;
    int idx = blockIdx.x * blockDim.x + threadIdx.x;
    if (idx >= total) return;
    if (idx < NMAT * MATSZ) {
        int mat = idx >> 14;
        int rem = idx & (MATSZ - 1);
        int i    = rem & 7;
        int lane = (rem >> 3) & 63;
        int ct   = (rem >> 9) & 7;
        int ks   = rem >> 12;
        int k   = ks * 32 + ((lane >> 4) & 3) * 8 + i;
        int col = ct * 16 + (lane & 15);
        float v;
        if (mat < 8)       v = cw[(size_t)mat * 129 * 128 + (size_t)k * 128 + col];
        else if (mat < 10) v = Wq[(size_t)(mat - 8) * MATSZ + (size_t)k * 128 + col];
        else               v = Wo[(size_t)(mat - 10) * MATSZ + (size_t)k * 128 + col];
        unsigned short hb = bf16rne(v);
        float rest = v - bf16f(hb);
        pkh[idx] = (short)hb;
        pkl[idx] = (short)bf16rne(rest);
    } else {
        int b = idx - NMAT * MATSZ;
        int mat = b >> 7, col = b & 127;
        float v;
        if (mat < 8)       v = cw[(size_t)mat * 129 * 128 + (size_t)128 * 128 + col];
        else if (mat < 10) v = bq[(mat - 8) * HIDN + col];
        else               v = bo[(mat - 10) * HIDN + col];
        bias[b] = v;
    }
}

// All four node types in one launch. seg: 0=user,1=item,2=taste,3=image.
// k/v -> bf16 tables at the type's row base; q (user/item) -> fp32.
__global__ __launch_bounds__(256) void mfma_proj_all(
    const float* __restrict__ xu, const float* __restrict__ xi,
    const float* __restrict__ xt, const float* __restrict__ xg,
    const short* __restrict__ pkh, const short* __restrict__ pkl,
    const float* __restrict__ bias,
    unsigned short* __restrict__ krb, unsigned short* __restrict__ vrb,
    float* __restrict__ q_u, float* __restrict__ q_i)
{
    int b = blockIdx.x;
    int seg, bloc;
    if (b < NBU)                  { seg = 0; bloc = b; }
    else if (b < NBU + NBI)       { seg = 1; bloc = b - NBU; }
    else if (b < NBU + NBI + NBT) { seg = 2; bloc = b - NBU - NBI; }
    else                          { seg = 3; bloc = b - NBU - NBI - NBT; }
    const float* x = (seg == 0) ? xu : (seg == 1) ? xi : (seg == 2) ? xt : xg;
    const int M     = (seg == 0) ? NU : (seg == 1) ? NI : (seg == 2) ? NT : NG;
    const int rbase = (seg == 0) ? BASE_U : (seg == 1) ? BASE_I : (seg == 2) ? BASE_T : BASE_G;
    float* qp = (seg == 0) ? q_u : (seg == 1) ? q_i : nullptr;

    __shared__ float xs[64 * XP];
    const int t  = threadIdx.x;
    const int r0 = bloc * 64;
    const int rows = min(64, M - r0);

#pragma unroll
    for (int p = 0; p < 8; ++p) {
        int f = p * 256 + t;
        int row = f >> 5, c4 = f & 31;
        float4 v = make_float4(0.f, 0.f, 0.f, 0.f);
        if (row < rows) v = *(const float4*)(x + (size_t)(r0 + row) * HIDN + c4 * 4);
        *(float4*)&xs[row * XP + c4 * 4] = v;
    }
    __syncthreads();

    const int l = t & 63, w = t >> 6;
    const int arow = w * 16 + (l & 15);
    const int kgrp = l >> 4;

    short8v ahi[4], alo[4];
#pragma unroll
    for (int ks = 0; ks < 4; ++ks) {
        const float* xp = &xs[arow * XP + ks * 32 + kgrp * 8];
        float4 va = *(const float4*)xp;
        float4 vb = *(const float4*)(xp + 4);
        float vv[8] = {va.x, va.y, va.z, va.w, vb.x, vb.y, vb.z, vb.w};
#pragma unroll
        for (int i = 0; i < 8; ++i) {
            unsigned short hb = bf16rne(vv[i]);
            ahi[ks][i] = (short)hb;
            alo[ks][i] = (short)bf16rne(vv[i] - bf16f(hb));
        }
    }

    for (int mi = 0; mi < 3; ++mi) {
        if (mi == 2 && qp == nullptr) break;
        const int mat = (mi == 0) ? seg : (mi == 1) ? (4 + seg) : (8 + seg);  // seg<2 for q
        const short8v* bh = (const short8v*)(pkh + (size_t)mat * MATSZ);
        const short8v* bl = (const short8v*)(pkl + (size_t)mat * MATSZ);
        const float*   bs = bias + mat * HIDN;

        f32x4 acc[8];
        f32x4 z; z[0] = 0.f; z[1] = 0.f; z[2] = 0.f; z[3] = 0.f;
#pragma unroll
        for (int ct = 0; ct < 8; ++ct) acc[ct] = z;

#pragma unroll
        for (int ct = 0; ct < 8; ++ct) {
#pragma unroll
            for (int ks = 0; ks < 4; ++ks) {
                short8v b1 = bh[(ks * 8 + ct) * 64 + l];
                short8v b2 = bl[(ks * 8 + ct) * 64 + l];
                acc[ct] = __builtin_amdgcn_mfma_f32_16x16x32_bf16(ahi[ks], b1, acc[ct], 0, 0, 0);
                acc[ct] = __builtin_amdgcn_mfma_f32_16x16x32_bf16(alo[ks], b1, acc[ct], 0, 0, 0);
                acc[ct] = __builtin_amdgcn_mfma_f32_16x16x32_bf16(ahi[ks], b2, acc[ct], 0, 0, 0);
            }
        }

        const int crow0 = w * 16 + kgrp * 4;
        const int ccol  = l & 15;
        if (mi < 2) {
            unsigned short* dst = (mi == 0) ? krb : vrb;
#pragma unroll
            for (int ct = 0; ct < 8; ++ct) {
                float bv = bs[ct * 16 + ccol];
#pragma unroll
                for (int j = 0; j < 4; ++j) {
                    int grow = r0 + crow0 + j;
                    if (grow < M)
                        dst[(size_t)(rbase + grow) * HIDN + ct * 16 + ccol] = bf16rne(acc[ct][j] + bv);
                }
            }
        } else {
#pragma unroll
            for (int ct = 0; ct < 8; ++ct) {
                float bv = bs[ct * 16 + ccol];
#pragma unroll
                for (int j = 0; j < 4; ++j) {
                    int grow = r0 + crow0 + j;
                    if (grow < M)
                        qp[(size_t)grow * HIDN + ct * 16 + ccol] = acc[ct][j] + bv;
                }
            }
        }
    }
}

// Both epilogues in one launch: seg0 item (mat 10), seg1 user (mat 11).
__global__ __launch_bounds__(256) void mfma_out_all(
    const float* __restrict__ agg_i, const float* __restrict__ agg_u,
    const short* __restrict__ pkh, const short* __restrict__ pkl,
    const float* __restrict__ bias,
    const float* __restrict__ x_item, const float* __restrict__ x_user,
    const float* __restrict__ skip_ptr,
    float* __restrict__ outp)
{
    int b = blockIdx.x;
    int seg = (b < NBI) ? 0 : 1;
    int bloc = (seg == 0) ? b : b - NBI;
    const float* agg = (seg == 0) ? agg_i : agg_u;
    const float* xin = (seg == 0) ? x_item : x_user;
    const int M = (seg == 0) ? NI : NU;
    const int mat = 10 + seg;
    float* out = (seg == 0) ? outp : outp + (size_t)NI * HIDN;

    __shared__ float xs[64 * XP];
    const int t  = threadIdx.x;
    const int r0 = bloc * 64;
    const int rows = min(64, M - r0);

#pragma unroll
    for (int p = 0; p < 8; ++p) {
        int f = p * 256 + t;
        int row = f >> 5, c4 = f & 31;
        float4 v = make_float4(0.f, 0.f, 0.f, 0.f);
        if (row < rows) v = *(const float4*)(agg + (size_t)(r0 + row) * HIDN + c4 * 4);
        *(float4*)&xs[row * XP + c4 * 4] = v;
    }
    __syncthreads();

    const int l = t & 63, w = t >> 6;
    const int arow = w * 16 + (l & 15);
    const int kgrp = l >> 4;

    short8v ahi[4], alo[4];
#pragma unroll
    for (int ks = 0; ks < 4; ++ks) {
        const float* xp = &xs[arow * XP + ks * 32 + kgrp * 8];
        float4 va = *(const float4*)xp;
        float4 vb = *(const float4*)(xp + 4);
        float vv[8] = {va.x, va.y, va.z, va.w, vb.x, vb.y, vb.z, vb.w};
#pragma unroll
        for (int i = 0; i < 8; ++i) {
            float g = 0.5f * vv[i] * (1.0f + erff(vv[i] * 0.70710678118654752440f));
            unsigned short hb = bf16rne(g);
            ahi[ks][i] = (short)hb;
            alo[ks][i] = (short)bf16rne(g - bf16f(hb));
        }
    }

    const short8v* bh = (const short8v*)(pkh + (size_t)mat * MATSZ);
    const short8v* bl = (const short8v*)(pkl + (size_t)mat * MATSZ);
    const float*   bs = bias + mat * HIDN;

    f32x4 acc[8];
    f32x4 z; z[0] = 0.f; z[1] = 0.f; z[2] = 0.f; z[3] = 0.f;
#pragma unroll
    for (int ct = 0; ct < 8; ++ct) acc[ct] = z;

#pragma unroll
    for (int ct = 0; ct < 8; ++ct) {
#pragma unroll
        for (int ks = 0; ks < 4; ++ks) {
            short8v b1 = bh[(ks * 8 + ct) * 64 + l];
            short8v b2 = bl[(ks * 8 + ct) * 64 + l];
            acc[ct] = __builtin_amdgcn_mfma_f32_16x16x32_bf16(ahi[ks], b1, acc[ct], 0, 0, 0);
            acc[ct] = __builtin_amdgcn_mfma_f32_16x16x32_bf16(alo[ks], b1, acc[ct], 0, 0, 0);
            acc[ct] = __builtin_amdgcn_mfma_f32_16x16x32_bf16(ahi[ks], b2, acc[ct], 0, 0, 0);
        }
    }

    const float gate = 1.f / (1.f + expf(-skip_ptr[seg]));
    const int crow0 = w * 16 + kgrp * 4;
    const int ccol  = l & 15;
#pragma unroll
    for (int ct = 0; ct < 8; ++ct) {
        float bv = bs[ct * 16 + ccol];
#pragma unroll
        for (int j = 0; j < 4; ++j) {
            int grow = r0 + crow0 + j;
            if (grow < M) {
                size_t o = (size_t)grow * HIDN + ct * 16 + ccol;
                out[o] = gate * (acc[ct][j] + bv) + (1.f - gate) * xin[o];
            }
        }
    }
}

// ----------------------- CSR construction -----------------------

__global__ void hist_kernel(const int* __restrict__ ti_dst, const int* __restrict__ im_dst,
                            const int* __restrict__ ub_dst, const int* __restrict__ bu_dst,
                            int* __restrict__ deg)
{
    int i = blockIdx.x * blockDim.x + threadIdx.x;
    if (i >= ETOT) return;
    int d;
    if (i < E_TI)                     d = ti_dst[i];
    else if (i < E_TI + E_IM)         d = im_dst[i - E_TI];
    else if (i < E_TI + E_IM + E_UB)  d = ub_dst[i - E_TI - E_IM];
    else                              d = NI + bu_dst[i - E_TI - E_IM - E_UB];
    atomicAdd(&deg[d], 1);
}

__global__ void scan1_kernel(int* __restrict__ deg, int* __restrict__ tops, int n)
{
    __shared__ int sh[256];
    int i = blockIdx.x * 256 + threadIdx.x;
    int v = (i < n) ? deg[i] : 0;
    sh[threadIdx.x] = v;
    __syncthreads();
    for (int o = 1; o < 256; o <<= 1) {
        int t = (threadIdx.x >= o) ? sh[threadIdx.x - o] : 0;
        __syncthreads();
        sh[threadIdx.x] += t;
        __syncthreads();
    }
    if (i < n) deg[i] = sh[threadIdx.x];
    if (threadIdx.x == 255) tops[blockIdx.x] = sh[255];
}

__global__ void scan2_kernel(int* __restrict__ tops, int nb)
{
    __shared__ int sh[1024];
    int v = (threadIdx.x < nb) ? tops[threadIdx.x] : 0;
    sh[threadIdx.x] = v;
    __syncthreads();
    for (int o = 1; o < 1024; o <<= 1) {
        int t = (threadIdx.x >= o) ? sh[threadIdx.x - o] : 0;
        __syncthreads();
        sh[threadIdx.x] += t;
        __syncthreads();
    }
    if (threadIdx.x < nb) tops[threadIdx.x] = sh[threadIdx.x];
}

__global__ void scan3_kernel(const int* __restrict__ part, const int* __restrict__ tops,
                             int* __restrict__ rowptr, int* __restrict__ cursor, int n)
{
    int i = blockIdx.x * 256 + threadIdx.x;
    if (i >= n) return;
    int add = (blockIdx.x > 0) ? tops[blockIdx.x - 1] : 0;
    int prev = (i > 0) ? ((threadIdx.x > 0) ? part[i - 1] + add
                                            : ((blockIdx.x > 0) ? tops[blockIdx.x - 1] : 0))
                       : 0;
    // prev = exclusive prefix at i
    rowptr[i + 1] = part[i] + add;
    cursor[i] = prev;
    if (i == 0) rowptr[0] = 0;
}

// col entry: (src_row << 2) | edge_type
__global__ void scatter_kernel(const int* __restrict__ ti_src, const int* __restrict__ ti_dst,
                               const int* __restrict__ im_src, const int* __restrict__ im_dst,
                               const int* __restrict__ ub_src, const int* __restrict__ ub_dst,
                               const int* __restrict__ bu_src, const int* __restrict__ bu_dst,
                               int* __restrict__ cursor, int* __restrict__ col)
{
    int i = blockIdx.x * blockDim.x + threadIdx.x;
    if (i >= ETOT) return;
    int d, row, et;
    if (i < E_TI)                    { d = ti_dst[i];                 row = BASE_T + ti_src[i];                 et = 0; }
    else if (i < E_TI + E_IM)        { int e = i - E_TI;              row = BASE_G + im_src[e]; d = im_dst[e];  et = 1; }
    else if (i < E_TI + E_IM + E_UB) { int e = i - E_TI - E_IM;       row = BASE_U + ub_src[e]; d = ub_dst[e];  et = 2; }
    else                             { int e = i - E_TI - E_IM - E_UB; row = BASE_I + bu_src[e]; d = NI + bu_dst[e]; et = 3; }
    int p = atomicAdd(&cursor[d], 1);
    col[p] = (row << 2) | et;
}

// ------------------- fused edge softmax-attention (online, one pass) -------------------
// One wave per dst. Running (m, ax, ay, den); rescale on max update. No scratch.
__global__ __launch_bounds__(256) void f12_kernel(
    const int* __restrict__ rowptr, const int* __restrict__ rowend,
    const int* __restrict__ col,
    const unsigned int* __restrict__ krw,   // bf16x2 per uint, row stride 64
    const float* __restrict__ q_i, const float* __restrict__ q_u,
    const unsigned int* __restrict__ vrw,
    const float* __restrict__ prel,
    float* __restrict__ agg_i, float* __restrict__ agg_u)
{
    int wid = (blockIdx.x << 2) + (threadIdx.x >> 6);
    if (wid >= ND) return;
    const int l = threadIdx.x & 63;
    const int h = l >> 3;

    const float* qrow = (wid < NI) ? q_i + (size_t)wid * HIDN
                                   : q_u + (size_t)(wid - NI) * HIDN;
    float2 qv = *(const float2*)(qrow + 2 * l);
    const float pr0 = prel[h]      * 0.25f;
    const float pr1 = prel[8 + h]  * 0.25f;
    const float pr2 = prel[16 + h] * 0.25f;
    const float pr3 = prel[24 + h] * 0.25f;

    const int start = rowptr[wid], end = rowend[wid];
    float m = -3.0e38f, ax = 0.f, ay = 0.f, den = 0.f;

    int p = start;
    for (; p + 1 < end; p += 2) {
        int pk0 = col[p], pk1 = col[p + 1];
        unsigned int u0 = krw[(size_t)(pk0 >> 2) * 64 + l];
        unsigned int u1 = krw[(size_t)(pk1 >> 2) * 64 + l];
        unsigned int v0 = vrw[(size_t)(pk0 >> 2) * 64 + l];
        unsigned int v1 = vrw[(size_t)(pk1 >> 2) * 64 + l];
        float d0 = qv.x * bflo(u0) + qv.y * bfhi(u0);
        float d1 = qv.x * bflo(u1) + qv.y * bfhi(u1);
        d0 += __shfl_xor(d0, 1); d1 += __shfl_xor(d1, 1);
        d0 += __shfl_xor(d0, 2); d1 += __shfl_xor(d1, 2);
        d0 += __shfl_xor(d0, 4); d1 += __shfl_xor(d1, 4);
        int e0t = pk0 & 3, e1t = pk1 & 3;
        float f0 = (e0t & 2) ? ((e0t & 1) ? pr3 : pr2) : ((e0t & 1) ? pr1 : pr0);
        float f1 = (e1t & 2) ? ((e1t & 1) ? pr3 : pr2) : ((e1t & 1) ? pr1 : pr0);
        float a0 = d0 * f0;
        float a1 = d1 * f1;
        float mn = fmaxf(m, fmaxf(a0, a1));
        float s  = __expf(m - mn);
        float e0 = __expf(a0 - mn);
        float e1 = __expf(a1 - mn);
        ax = ax * s + e0 * bflo(v0) + e1 * bflo(v1);
        ay = ay * s + e0 * bfhi(v0) + e1 * bfhi(v1);
        den = den * s + e0 + e1;
        m = mn;
    }
    if (p < end) {
        int pk0 = col[p];
        unsigned int u0 = krw[(size_t)(pk0 >> 2) * 64 + l];
        unsigned int v0 = vrw[(size_t)(pk0 >> 2) * 64 + l];
        float d0 = qv.x * bflo(u0) + qv.y * bfhi(u0);
        d0 += __shfl_xor(d0, 1);
        d0 += __shfl_xor(d0, 2);
        d0 += __shfl_xor(d0, 4);
        int e0t = pk0 & 3;
        float f0 = (e0t & 2) ? ((e0t & 1) ? pr3 : pr2) : ((e0t & 1) ? pr1 : pr0);
        float a0 = d0 * f0;
        float mn = fmaxf(m, a0);
        float s  = __expf(m - mn);
        float e0 = __expf(a0 - mn);
        ax = ax * s + e0 * bflo(v0);
        ay = ay * s + e0 * bfhi(v0);
        den = den * s + e0;
    }

    float inv = 1.f / (den + 1e-16f);
    float* dst = (wid < NI) ? agg_i + (size_t)wid * HIDN
                            : agg_u + (size_t)(wid - NI) * HIDN;
    *(float2*)(dst + 2 * l) = make_float2(ax * inv, ay * inv);
}

extern "C" void kernel_launch(void* const* d_in, const int* in_sizes, int n_in,
                              void* d_out, int out_size, void* d_ws, size_t ws_size,
                              hipStream_t stream)
{
    const float* x_user = (const float*)d_in[0];
    const float* x_item = (const float*)d_in[1];
    const float* x_taste= (const float*)d_in[2];
    const float* x_image= (const float*)d_in[3];
    const float* Wk     = (const float*)d_in[4];
    const float* bk     = (const float*)d_in[5];
    const float* Wq     = (const float*)d_in[6];
    const float* bq     = (const float*)d_in[7];
    const float* Wv     = (const float*)d_in[8];
    const float* bv     = (const float*)d_in[9];
    const float* a_rel  = (const float*)d_in[10];
    const float* m_rel  = (const float*)d_in[11];
    const float* p_rel  = (const float*)d_in[12];
    const float* Wo     = (const float*)d_in[13];
    const float* bo     = (const float*)d_in[14];
    const float* skip   = (const float*)d_in[15];
    const int* ti_src = (const int*)d_in[16];
    const int* ti_dst = (const int*)d_in[17];
    const int* im_src = (const int*)d_in[18];
    const int* im_dst = (const int*)d_in[19];
    const int* ub_src = (const int*)d_in[20];
    const int* ub_dst = (const int*)d_in[21];
    const int* bu_src = (const int*)d_in[22];
    const int* bu_dst = (const int*)d_in[23];

    float* ws = (float*)d_ws;
    float* outp = (float*)d_out;
    (void)in_sizes; (void)n_in; (void)out_size;

    // ---- workspace layout (floats) ----
    size_t off = 0;
    auto alloc = [&](size_t n) { size_t o = off; off += n; return o; };
    const size_t o_cw   = alloc((size_t)2 * 4 * 129 * 128);   // reused as deg[] after pack
    const size_t o_pkh  = alloc((size_t)NMAT * MATSZ / 2);
    const size_t o_pkl  = alloc((size_t)NMAT * MATSZ / 2);
    const size_t o_bias = alloc((size_t)NMAT * HIDN);
    const size_t o_krb  = alloc((size_t)(NU + NI + NT + NG) * HIDN / 2);  // bf16 table
    const size_t o_vrb  = alloc((size_t)(NU + NI + NT + NG) * HIDN / 2);  // bf16 table
    const size_t o_q_i  = alloc((size_t)NI * HIDN);
    const size_t o_q_u  = alloc((size_t)NU * HIDN);
    const size_t o_agg  = alloc((size_t)(NI + NU) * HIDN);
    const size_t o_int  = alloc((size_t)(ND + 1) + ND + 1024 + ETOT);

    if (ws_size < off * sizeof(float)) return;  // clean failure instead of OOB fault

    unsigned short* krb = (unsigned short*)(ws + o_krb);
    unsigned short* vrb = (unsigned short*)(ws + o_vrb);

    short* pkh  = (short*)(ws + o_pkh);
    short* pkl  = (short*)(ws + o_pkl);
    float* bias = ws + o_bias;

    int* deg    = (int*)(ws + o_cw);        // overlays cw (dead after pack)
    int* rowptr = (int*)(ws + o_int);
    int* cursor = rowptr + (ND + 1);
    int* tops   = cursor + ND;
    int* col    = tops + 1024;

    float* agg_i = ws + o_agg;
    float* agg_u = ws + o_agg + (size_t)NI * HIDN;

    // ---- 1. combined weights + MFMA pack ----
    {
        int total = 2 * 4 * 129 * 128;
        build_cw_kernel<<<(total + 255) / 256, 256, 0, stream>>>(
            Wk, bk, Wv, bv, a_rel, m_rel, ws + o_cw);
        int ptotal = NMAT * MATSZ + NMAT * HIDN;
        pack_kernel<<<(ptotal + 255) / 256, 256, 0, stream>>>(
            ws + o_cw, Wq, bq, Wo, bo, pkh, pkl, bias);
    }

    // ---- 2. projections: ONE launch for all four node types ----
    mfma_proj_all<<<NBU + NBI + NBT + NBG, 256, 0, stream>>>(
        x_user, x_item, x_taste, x_image, pkh, pkl, bias,
        krb, vrb, ws + o_q_u, ws + o_q_i);

    // ---- 3. CSR build ----
    hipMemsetAsync(deg, 0, ND * sizeof(int), stream);
    hist_kernel<<<(ETOT + 255) / 256, 256, 0, stream>>>(ti_dst, im_dst, ub_dst, bu_dst, deg);
    const int NB1 = (ND + 255) / 256;
    scan1_kernel<<<NB1, 256, 0, stream>>>(deg, tops, ND);
    scan2_kernel<<<1, 1024, 0, stream>>>(tops, NB1);
    scan3_kernel<<<NB1, 256, 0, stream>>>(deg, tops, rowptr, cursor, ND);
    scatter_kernel<<<(ETOT + 255) / 256, 256, 0, stream>>>(
        ti_src, ti_dst, im_src, im_dst, ub_src, ub_dst, bu_src, bu_dst, cursor, col);
    // after scatter, cursor[d] == row end

    // ---- 4. fused online-softmax edge aggregation ----
    const int NBW = (ND + 3) / 4;
    f12_kernel<<<NBW, 256, 0, stream>>>(
        rowptr, cursor, col,
        (const unsigned int*)krb, ws + o_q_i, ws + o_q_u,
        (const unsigned int*)vrb, p_rel,
        agg_i, agg_u);

    // ---- 5. epilogue: ONE launch for both outputs ----
    mfma_out_all<<<NBI + NBU, 256, 0, stream>>>(
        agg_i, agg_u, pkh, pkl, bias, x_item, x_user, skip, outp);
}